// Round 1
// baseline (8103.452 us; speedup 1.0000x reference)
//
#include <hip/hip_runtime.h>
#include <math.h>

#define NNODES 5000
#define NEDGES 50000
#define BATCH 8
#define SEQT 12
#define HIDC 64
#define NB (NNODES*BATCH)
#define MAXDEG 128

// ---------------- setup kernels ----------------

__global__ void count_deg_k(const int* __restrict__ ei, int* deg_out, int* deg_in){
    int e = blockIdx.x*blockDim.x + threadIdx.x;
    if (e < NEDGES){
        atomicAdd(&deg_out[ei[e]], 1);
        atomicAdd(&deg_in[ei[NEDGES + e]], 1);
    }
}

__global__ void scan_k(const int* __restrict__ deg_in, int* __restrict__ row_ptr){
    __shared__ int part[256];
    int tid = threadIdx.x;
    int base = tid*20;
    int loc[20]; int s = 0;
    for (int i=0;i<20;i++){
        int idx = base+i;
        int v = (idx < NNODES) ? deg_in[idx] : 0;
        loc[i] = s; s += v;
    }
    part[tid] = s;
    __syncthreads();
    for (int off=1; off<256; off<<=1){
        int v = (tid>=off) ? part[tid-off] : 0;
        __syncthreads();
        part[tid] += v;
        __syncthreads();
    }
    int prev = (tid==0) ? 0 : part[tid-1];
    for (int i=0;i<20;i++){
        int idx = base+i;
        if (idx < NNODES) row_ptr[idx] = prev + loc[i];
    }
    if (tid==255) row_ptr[NNODES] = part[255];
}

__global__ void fill_csr_k(const int* __restrict__ ei, const int* __restrict__ deg_out,
                           const int* __restrict__ deg_in, const int* __restrict__ row_ptr,
                           int* cursor, int* __restrict__ csr_src,
                           float* __restrict__ csr_wo, float* __restrict__ csr_wi){
    int e = blockIdx.x*blockDim.x + threadIdx.x;
    if (e >= NEDGES) return;
    int s = ei[e], d = ei[NEDGES+e];
    int pos = atomicAdd(&cursor[d], 1);
    int slot = row_ptr[d] + pos;
    csr_src[slot] = s;
    csr_wo[slot] = 1.f/(float)deg_out[s];   // src of edge e -> deg_out[s] >= 1
    csr_wi[slot] = 1.f/(float)deg_in[d];    // dst of edge e -> deg_in[d] >= 1
}

// ---------------- basis construction ----------------

// X0[row][0:Fa] = Xin ; X0[row][Fa:Fa+64] = H (optionally * R from ZR buffer)
__global__ void build_x0_k(const float* __restrict__ xin, int layer0, int t,
                           const float* __restrict__ H, const float* __restrict__ Rbuf,
                           float* __restrict__ X0, int F){
    int idx = blockIdx.x*blockDim.x + threadIdx.x;
    int total = NB*F;
    if (idx >= total) return;
    int row = idx / F, f = idx - row*F;
    int Fa = F - HIDC;
    float v;
    if (f < Fa){
        if (layer0){
            int n = row >> 3, b = row & 7;           // row = n*BATCH + b
            v = xin[ ((size_t)(b*SEQT + t)*NNODES + n)*2 + f ];
        } else {
            v = xin[(size_t)row*HIDC + f];
        }
    } else {
        int j = f - Fa;
        v = H[(size_t)row*HIDC + j];
        if (Rbuf) v *= Rbuf[(size_t)row*128 + 64 + j];
    }
    X0[idx] = v;
}

// ---------------- propagation (CSR by dst, no atomics) ----------------

// Yo[n] = sum_e wo_e X[src_e] ; Yi[n] = sum_e wi_e X[src_e] (single gather for both)
__global__ void prop_dual_k(const float* __restrict__ X,
                            float* __restrict__ Yo, float* __restrict__ Yi,
                            const int* __restrict__ row_ptr, const int* __restrict__ csr_src,
                            const float* __restrict__ csr_wo, const float* __restrict__ csr_wi,
                            int F){
    int n = blockIdx.x;
    int beg = row_ptr[n], end = row_ptr[n+1];
    int deg = end - beg;
    int nst = deg < MAXDEG ? deg : MAXDEG;
    __shared__ int s_src[MAXDEG]; __shared__ float s_wo[MAXDEG], s_wi[MAXDEG];
    int BF = 8*F;
    for (int j = threadIdx.x; j < nst; j += blockDim.x){
        s_src[j] = csr_src[beg+j]*BF;
        s_wo[j] = csr_wo[beg+j];
        s_wi[j] = csr_wi[beg+j];
    }
    __syncthreads();
    size_t outb = (size_t)n*BF;
    for (int i = threadIdx.x; i < BF; i += blockDim.x){
        float ao = 0.f, ai = 0.f;
        for (int j=0;j<nst;j++){
            float xv = X[(size_t)s_src[j] + i];
            ao += s_wo[j]*xv;
            ai += s_wi[j]*xv;
        }
        for (int j=nst;j<deg;j++){
            float xv = X[(size_t)csr_src[beg+j]*BF + i];
            ao += csr_wo[beg+j]*xv;
            ai += csr_wi[beg+j]*xv;
        }
        Yo[outb+i] = ao;
        Yi[outb+i] = ai;
    }
}

// Y2 = 2*prop(X1, w) - X0 ; blockIdx.y selects (out-norm) or (in-norm) path
__global__ void prop2_k(const float* __restrict__ X1o, const float* __restrict__ X1i,
                        const float* __restrict__ X0,
                        float* __restrict__ Y2o, float* __restrict__ Y2i,
                        const int* __restrict__ row_ptr, const int* __restrict__ csr_src,
                        const float* __restrict__ csr_wo, const float* __restrict__ csr_wi,
                        int F){
    int n = blockIdx.x;
    int which = blockIdx.y;
    const float* Xin = which ? X1i : X1o;
    const float* wsrc = which ? csr_wi : csr_wo;
    float* Y = which ? Y2i : Y2o;
    int beg = row_ptr[n], end = row_ptr[n+1];
    int deg = end - beg;
    int nst = deg < MAXDEG ? deg : MAXDEG;
    __shared__ int s_src[MAXDEG]; __shared__ float s_w[MAXDEG];
    int BF = 8*F;
    for (int j = threadIdx.x; j < nst; j += blockDim.x){
        s_src[j] = csr_src[beg+j]*BF;
        s_w[j] = wsrc[beg+j];
    }
    __syncthreads();
    size_t outb = (size_t)n*BF;
    for (int i = threadIdx.x; i < BF; i += blockDim.x){
        float acc = 0.f;
        for (int j=0;j<nst;j++){
            acc += s_w[j]*Xin[(size_t)s_src[j] + i];
        }
        for (int j=nst;j<deg;j++){
            acc += wsrc[beg+j]*Xin[(size_t)csr_src[beg+j]*BF + i];
        }
        Y[outb+i] = 2.f*acc - X0[outb+i];
    }
}

// ---------------- fused dconv GEMM ----------------
// C[40000 x 64] = sum over 5 bases A_kb[40000 x F] @ Wslice_kb[F x 64] (+ bias)
// epi 0: ZR[row*128 + gy*64 + col] = sigmoid(C)       (gy=0 -> Z with W0, gy=1 -> R with W1)
// epi 1: Hst[row*64+col] = Z*Hold + (1-Z)*tanh(C)     (GRU update, reads Z from ZR)
__global__ __launch_bounds__(256) void dconv_gemm_k(
        const float* __restrict__ XB, int F,
        const float* __restrict__ W0, const float* __restrict__ b0,
        const float* __restrict__ W1, const float* __restrict__ b1,
        float* __restrict__ ZR,
        float* __restrict__ Hst,
        int epi){
    __shared__ float As[16][68];
    __shared__ float Bs[16][68];
    const int tid = threadIdx.x;
    const int tx = tid & 15, ty = tid >> 4;
    const int m0 = blockIdx.x * 64;
    const int gy = blockIdx.y;
    const float* W = gy ? W1 : W0;
    const float* bias = gy ? b1 : b0;
    float acc[4][4] = {};
    const int dmap[5] = {0,0,1,0,1};
    const int kmap[5] = {0,1,1,2,2};
    for (int kb=0; kb<5; ++kb){
        const float* A = XB + (size_t)kb*NB*F;
        const float* Wk = W + (size_t)(dmap[kb]*3 + kmap[kb])*F*64;
        const float* Wk2 = (kb==0) ? (W + (size_t)3*F*64) : nullptr;  // (d=1,k=0)
        for (int f0=0; f0<F; f0+=16){
            {   // A tile -> transposed LDS [fi][row]
                int fi = tid & 15, r0 = tid >> 4;
                int f = f0 + fi;
                const bool ok = (f < F);
                #pragma unroll
                for (int j=0;j<4;j++){
                    int r = r0 + j*16;
                    As[fi][r] = ok ? A[(size_t)(m0+r)*F + f] : 0.f;
                }
            }
            {   // B tile [fi][h]
                int fi = tid >> 4; int h4 = (tid & 15)*4;
                int f = f0 + fi;
                float4 w = make_float4(0.f,0.f,0.f,0.f);
                if (f < F){
                    w = *(const float4*)(Wk + (size_t)f*64 + h4);
                    if (Wk2){
                        float4 w2 = *(const float4*)(Wk2 + (size_t)f*64 + h4);
                        w.x+=w2.x; w.y+=w2.y; w.z+=w2.z; w.w+=w2.w;
                    }
                }
                *(float4*)&Bs[fi][h4] = w;
            }
            __syncthreads();
            #pragma unroll
            for (int k=0;k<16;k++){
                float4 a = *(const float4*)&As[k][ty*4];
                float4 b = *(const float4*)&Bs[k][tx*4];
                float av[4] = {a.x,a.y,a.z,a.w};
                float bv[4] = {b.x,b.y,b.z,b.w};
                #pragma unroll
                for (int i=0;i<4;i++)
                    #pragma unroll
                    for (int j=0;j<4;j++)
                        acc[i][j] = fmaf(av[i], bv[j], acc[i][j]);
            }
            __syncthreads();
        }
    }
    #pragma unroll
    for (int i=0;i<4;i++){
        int row = m0 + ty*4 + i;
        #pragma unroll
        for (int j=0;j<4;j++){
            int col = tx*4 + j;
            float v = acc[i][j] + bias[col];
            if (epi == 0){
                ZR[(size_t)row*128 + gy*64 + col] = 1.f/(1.f+__expf(-v));
            } else {
                float ht = tanhf(v);
                float z = ZR[(size_t)row*128 + col];
                size_t hidx = (size_t)row*HIDC + col;
                float hold = Hst[hidx];
                Hst[hidx] = z*hold + (1.f-z)*ht;
            }
        }
    }
}

// ---------------- output projection ----------------
__global__ void proj_k(const float* __restrict__ h1, const float* __restrict__ Wo,
                       const float* __restrict__ bo, float* __restrict__ out, int t){
    int idx = blockIdx.x*blockDim.x + threadIdx.x;
    if (idx >= NB) return;
    int b = idx / NNODES, n = idx - b*NNODES;
    const float* hp = h1 + ((size_t)(n*BATCH + b))*HIDC;
    float s = 0.f;
    #pragma unroll
    for (int j=0;j<64;j+=4){
        float4 hv = *(const float4*)(hp+j);
        float4 wv = *(const float4*)(Wo+j);
        s += hv.x*wv.x + hv.y*wv.y + hv.z*wv.z + hv.w*wv.w;
    }
    out[((size_t)(b*SEQT + t))*NNODES + n] = s + bo[0];
}

// ---------------- launcher ----------------

extern "C" void kernel_launch(void* const* d_in, const int* in_sizes, int n_in,
                              void* d_out, int out_size, void* d_ws, size_t ws_size,
                              hipStream_t stream){
    (void)in_sizes; (void)n_in; (void)out_size; (void)ws_size;
    const float* x  = (const float*)d_in[0];
    const int*   ei = (const int*)d_in[1];
    const float* Wz[2] = {(const float*)d_in[2],  (const float*)d_in[8]};
    const float* bz[2] = {(const float*)d_in[3],  (const float*)d_in[9]};
    const float* Wr[2] = {(const float*)d_in[4],  (const float*)d_in[10]};
    const float* br[2] = {(const float*)d_in[5],  (const float*)d_in[11]};
    const float* Wh[2] = {(const float*)d_in[6],  (const float*)d_in[12]};
    const float* bh[2] = {(const float*)d_in[7],  (const float*)d_in[13]};
    const float* Wo = (const float*)d_in[14];
    const float* bo = (const float*)d_in[15];
    float* out = (float*)d_out;

    char* p = (char*)d_ws;
    auto alloc = [&](size_t bytes)->char*{
        char* r = p; p += (bytes + 255) & ~(size_t)255; return r;
    };
    float* h0 = (float*)alloc((size_t)NB*HIDC*4);
    float* h1 = (float*)alloc((size_t)NB*HIDC*4);
    float* XB = (float*)alloc((size_t)5*NB*128*4);
    float* ZR = (float*)alloc((size_t)NB*128*4);
    int* deg_out = (int*)alloc(NNODES*4);
    int* deg_in  = (int*)alloc(NNODES*4);
    int* row_ptr = (int*)alloc((NNODES+1)*4);
    int* cursor  = (int*)alloc(NNODES*4);
    int* csr_src = (int*)alloc(NEDGES*4);
    float* csr_wo = (float*)alloc(NEDGES*4);
    float* csr_wi = (float*)alloc(NEDGES*4);

    hipMemsetAsync(deg_out, 0, NNODES*4, stream);
    hipMemsetAsync(deg_in,  0, NNODES*4, stream);
    hipMemsetAsync(cursor,  0, NNODES*4, stream);
    hipMemsetAsync(h0, 0, (size_t)NB*HIDC*4, stream);
    hipMemsetAsync(h1, 0, (size_t)NB*HIDC*4, stream);

    count_deg_k<<<(NEDGES+255)/256, 256, 0, stream>>>(ei, deg_out, deg_in);
    scan_k<<<1, 256, 0, stream>>>(deg_in, row_ptr);
    fill_csr_k<<<(NEDGES+255)/256, 256, 0, stream>>>(ei, deg_out, deg_in, row_ptr,
                                                     cursor, csr_src, csr_wo, csr_wi);

    for (int t=0; t<SEQT; ++t){
        for (int l=0; l<2; ++l){
            const int F = (l==0) ? 66 : 128;
            const float* xin = (l==0) ? x : h0;
            float* H = (l==0) ? h0 : h1;
            size_t bstride = (size_t)NB*F;
            float* X0  = XB;
            float* X1o = XB + bstride;
            float* X1i = XB + 2*bstride;
            float* X2o = XB + 3*bstride;
            float* X2i = XB + 4*bstride;
            int nthr = NB*F;

            // -------- Z/R gates (shared basis) --------
            build_x0_k<<<(nthr+255)/256,256,0,stream>>>(xin, l==0, t, H, nullptr, X0, F);
            prop_dual_k<<<NNODES,256,0,stream>>>(X0, X1o, X1i, row_ptr, csr_src, csr_wo, csr_wi, F);
            prop2_k<<<dim3(NNODES,2),256,0,stream>>>(X1o, X1i, X0, X2o, X2i,
                                                     row_ptr, csr_src, csr_wo, csr_wi, F);
            dconv_gemm_k<<<dim3(NB/64,2),256,0,stream>>>(XB, F, Wz[l], bz[l], Wr[l], br[l],
                                                         ZR, nullptr, 0);
            // -------- candidate gate + GRU update --------
            build_x0_k<<<(nthr+255)/256,256,0,stream>>>(xin, l==0, t, H, ZR, X0, F);
            prop_dual_k<<<NNODES,256,0,stream>>>(X0, X1o, X1i, row_ptr, csr_src, csr_wo, csr_wi, F);
            prop2_k<<<dim3(NNODES,2),256,0,stream>>>(X1o, X1i, X0, X2o, X2i,
                                                     row_ptr, csr_src, csr_wo, csr_wi, F);
            dconv_gemm_k<<<dim3(NB/64,1),256,0,stream>>>(XB, F, Wh[l], bh[l], nullptr, nullptr,
                                                         ZR, H, 1);
        }
        proj_k<<<(NB+255)/256,256,0,stream>>>(h1, Wo, bo, out, t);
    }
}

// Round 2
// 5878.994 us; speedup vs baseline: 1.3784x; 1.3784x over previous
//
#include <hip/hip_runtime.h>
#include <math.h>

#define NNODES 5000
#define NEDGES 50000
#define BATCH 8
#define SEQT 12
#define NB (NNODES*BATCH)
#define MAXDEG 128

typedef __attribute__((ext_vector_type(8))) short bf16x8;
typedef __attribute__((ext_vector_type(4))) float f32x4;

// ---------- bf16 split helpers ----------
__device__ __forceinline__ unsigned short f2bf(float f){
    unsigned u = __float_as_uint(f);
    u += 0x7fffu + ((u>>16)&1u);
    return (unsigned short)(u>>16);
}
// packed dword: hi bf16 in low 16 bits, lo bf16 in high 16 bits
__device__ __forceinline__ unsigned packsplit(float v){
    unsigned short h = f2bf(v);
    float hf = __uint_as_float(((unsigned)h)<<16);
    unsigned short l = f2bf(v - hf);
    return (unsigned)h | ((unsigned)l<<16);
}
__device__ __forceinline__ float unpackf(unsigned d){
    return __uint_as_float(d<<16) + __uint_as_float(d & 0xffff0000u);
}

// ---------------- setup kernels ----------------

__global__ void count_deg_k(const int* __restrict__ ei, int* deg_out, int* deg_in){
    int e = blockIdx.x*blockDim.x + threadIdx.x;
    if (e < NEDGES){
        atomicAdd(&deg_out[ei[e]], 1);
        atomicAdd(&deg_in[ei[NEDGES + e]], 1);
    }
}

__global__ void scan_k(const int* __restrict__ deg_in, int* __restrict__ row_ptr){
    __shared__ int part[256];
    int tid = threadIdx.x;
    int base = tid*20;
    int loc[20]; int s = 0;
    for (int i=0;i<20;i++){
        int idx = base+i;
        int v = (idx < NNODES) ? deg_in[idx] : 0;
        loc[i] = s; s += v;
    }
    part[tid] = s;
    __syncthreads();
    for (int off=1; off<256; off<<=1){
        int v = (tid>=off) ? part[tid-off] : 0;
        __syncthreads();
        part[tid] += v;
        __syncthreads();
    }
    int prev = (tid==0) ? 0 : part[tid-1];
    for (int i=0;i<20;i++){
        int idx = base+i;
        if (idx < NNODES) row_ptr[idx] = prev + loc[i];
    }
    if (tid==255) row_ptr[NNODES] = part[255];
}

__global__ void fill_csr_k(const int* __restrict__ ei, const int* __restrict__ deg_out,
                           const int* __restrict__ deg_in, const int* __restrict__ row_ptr,
                           int* cursor, int* __restrict__ csr_src,
                           float* __restrict__ csr_wo, float* __restrict__ csr_wi){
    int e = blockIdx.x*blockDim.x + threadIdx.x;
    if (e >= NEDGES) return;
    int s = ei[e], d = ei[NEDGES+e];
    int pos = atomicAdd(&cursor[d], 1);
    int slot = row_ptr[d] + pos;
    csr_src[slot] = s;
    csr_wo[slot] = 1.f/(float)deg_out[s];
    csr_wi[slot] = 1.f/(float)deg_in[d];
}

// ---------------- weight packing (split bf16, MFMA fragment layout) ----------------
// Wp[cf][ks][lane][j]: lane provides B[k = ks*32+(lane>>4)*8+j][col = cf*16+(lane&15)]
__global__ void pack_w_k(const float* __restrict__ W, int F, int Fp, int NK,
                         short* __restrict__ wh, short* __restrict__ wl){
    int idx = blockIdx.x*256 + threadIdx.x;
    if (idx >= 4*NK*64) return;
    int lane = idx & 63;
    int rest = idx >> 6;
    int ks = rest % NK, cf = rest / NK;
    int col = cf*16 + (lane & 15);
    int kbase = ks*32 + (lane>>4)*8;
    size_t o = (size_t)idx*8;
    for (int j=0;j<8;j++){
        int kg = kbase + j;
        int kb = kg / Fp, kin = kg - kb*Fp;
        float v = 0.f;
        if (kin < F){
            int d, kk;
            if (kb==0){ d=0; kk=0; }
            else if (kb==1){ d=0; kk=1; }
            else if (kb==2){ d=1; kk=1; }
            else if (kb==3){ d=0; kk=2; }
            else { d=1; kk=2; }
            v = W[((size_t)(d*3+kk)*F + kin)*64 + col];
            if (kb==0) v += W[((size_t)(1*3+0)*F + kin)*64 + col];
        }
        unsigned short hh = f2bf(v);
        float hf = __uint_as_float(((unsigned)hh)<<16);
        unsigned short ll = f2bf(v - hf);
        wh[o+j] = (short)hh;
        wl[o+j] = (short)ll;
    }
}

// ---------------- basis build kernels ----------------

// layer0 X0 / X0h: [row][96] packed, cols 0..1 = x_t, 2..65 = h0 (optionally * R)
template<bool WITHR>
__global__ void build_x0_l0_k(const float* __restrict__ x, int t,
                              const float* __restrict__ h0f, const float* __restrict__ ZR,
                              unsigned* __restrict__ X0p){
    int idx = blockIdx.x*256 + threadIdx.x;
    if (idx >= NB*66) return;
    int row = idx / 66, f = idx - row*66;
    float v;
    if (f < 2){
        int n = row >> 3, b = row & 7;
        v = x[((size_t)(b*SEQT + t)*NNODES + n)*2 + f];
    } else {
        int c = f - 2;
        v = h0f[(size_t)row*64 + c];
        if (WITHR) v *= ZR[(size_t)row*128 + 64 + c];
    }
    X0p[(size_t)row*96 + f] = packsplit(v);
}

// layer1 G0 = h1 * R  [row][64] packed
__global__ void build_g0_k(const float* __restrict__ h1f, const float* __restrict__ ZR,
                           unsigned* __restrict__ G0p){
    int idx = blockIdx.x*256 + threadIdx.x;
    if (idx >= NB*64) return;
    int row = idx >> 6, c = idx & 63;
    float v = h1f[(size_t)row*64 + c] * ZR[(size_t)row*128 + 64 + c];
    G0p[idx] = packsplit(v);
}

// ---------------- propagation (packed in, packed out) ----------------

template<int F, int FpS, int FpO, bool TWOSRC>
__global__ __launch_bounds__(256) void prop_dual_p(
    const unsigned* __restrict__ Xa, const unsigned* __restrict__ Xb,
    unsigned* __restrict__ Yo, unsigned* __restrict__ Yi,
    const int* __restrict__ row_ptr, const int* __restrict__ csr_src,
    const float* __restrict__ csr_wo, const float* __restrict__ csr_wi){
    constexpr int F2 = F/2;
    constexpr int V = 8*F2;
    int n = blockIdx.x;
    int beg = row_ptr[n], end = row_ptr[n+1];
    int deg = end - beg;
    int nst = deg < MAXDEG ? deg : MAXDEG;
    __shared__ int s_s[MAXDEG]; __shared__ float s_wo[MAXDEG], s_wi[MAXDEG];
    for (int j = threadIdx.x; j < nst; j += 256){
        s_s[j] = csr_src[beg+j];
        s_wo[j] = csr_wo[beg+j];
        s_wi[j] = csr_wi[beg+j];
    }
    __syncthreads();
    for (int v = threadIdx.x; v < V; v += 256){
        int b = v / F2, f2 = v - b*F2;
        const unsigned* SA; int soff;
        if (TWOSRC){
            if (f2 < F2/2){ SA = Xa; soff = b*FpS + 2*f2; }
            else          { SA = Xb; soff = b*FpS + 2*(f2 - F2/2); }
        } else { SA = Xa; soff = b*FpS + 2*f2; }
        float ao0=0.f, ao1=0.f, ai0=0.f, ai1=0.f;
        for (int j=0;j<nst;j++){
            const unsigned* p = SA + (size_t)s_s[j]*(8*FpS) + soff;
            unsigned d0 = p[0], d1 = p[1];
            float x0 = unpackf(d0), x1 = unpackf(d1);
            float wo = s_wo[j], wi = s_wi[j];
            ao0 = fmaf(wo, x0, ao0); ao1 = fmaf(wo, x1, ao1);
            ai0 = fmaf(wi, x0, ai0); ai1 = fmaf(wi, x1, ai1);
        }
        for (int j=nst;j<deg;j++){
            const unsigned* p = SA + (size_t)csr_src[beg+j]*(8*FpS) + soff;
            unsigned d0 = p[0], d1 = p[1];
            float x0 = unpackf(d0), x1 = unpackf(d1);
            float wo = csr_wo[beg+j], wi = csr_wi[beg+j];
            ao0 = fmaf(wo, x0, ao0); ao1 = fmaf(wo, x1, ao1);
            ai0 = fmaf(wi, x0, ai0); ai1 = fmaf(wi, x1, ai1);
        }
        size_t o = (size_t)(n*8 + b)*FpO + 2*f2;
        Yo[o]   = packsplit(ao0); Yo[o+1] = packsplit(ao1);
        Yi[o]   = packsplit(ai0); Yi[o+1] = packsplit(ai1);
    }
}

// Y2 = 2*prop(X1,w) - X0 ; grid.y = direction
template<int F, int FpS, int FpO, int FpX, bool TWOX0>
__global__ __launch_bounds__(256) void prop2_p(
    const unsigned* __restrict__ X1o, const unsigned* __restrict__ X1i,
    const unsigned* __restrict__ X0a, const unsigned* __restrict__ X0b,
    unsigned* __restrict__ Y2o, unsigned* __restrict__ Y2i,
    const int* __restrict__ row_ptr, const int* __restrict__ csr_src,
    const float* __restrict__ csr_wo, const float* __restrict__ csr_wi){
    constexpr int F2 = F/2;
    constexpr int V = 8*F2;
    int n = blockIdx.x;
    const unsigned* X1 = blockIdx.y ? X1i : X1o;
    const float* wg = blockIdx.y ? csr_wi : csr_wo;
    unsigned* Y = blockIdx.y ? Y2i : Y2o;
    int beg = row_ptr[n], end = row_ptr[n+1];
    int deg = end - beg;
    int nst = deg < MAXDEG ? deg : MAXDEG;
    __shared__ int s_s[MAXDEG]; __shared__ float s_w[MAXDEG];
    for (int j = threadIdx.x; j < nst; j += 256){
        s_s[j] = csr_src[beg+j];
        s_w[j] = wg[beg+j];
    }
    __syncthreads();
    for (int v = threadIdx.x; v < V; v += 256){
        int b = v / F2, f2 = v - b*F2;
        int soff = b*FpS + 2*f2;
        float a0=0.f, a1=0.f;
        for (int j=0;j<nst;j++){
            const unsigned* p = X1 + (size_t)s_s[j]*(8*FpS) + soff;
            unsigned d0 = p[0], d1 = p[1];
            a0 = fmaf(s_w[j], unpackf(d0), a0);
            a1 = fmaf(s_w[j], unpackf(d1), a1);
        }
        for (int j=nst;j<deg;j++){
            const unsigned* p = X1 + (size_t)csr_src[beg+j]*(8*FpS) + soff;
            unsigned d0 = p[0], d1 = p[1];
            float w = wg[beg+j];
            a0 = fmaf(w, unpackf(d0), a0);
            a1 = fmaf(w, unpackf(d1), a1);
        }
        // X0 value at this output position
        const unsigned* XP; int xoff;
        if (TWOX0){
            if (f2 < F2/2){ XP = X0a; xoff = b*FpX + 2*f2; }
            else          { XP = X0b; xoff = b*FpX + 2*(f2 - F2/2); }
        } else { XP = X0a; xoff = b*FpX + 2*f2; }
        const unsigned* px = XP + (size_t)n*(8*FpX) + xoff;
        float x00 = unpackf(px[0]), x01 = unpackf(px[1]);
        size_t o = (size_t)(n*8 + b)*FpO + 2*f2;
        Y[o]   = packsplit(2.f*a0 - x00);
        Y[o+1] = packsplit(2.f*a1 - x01);
    }
}

// ---------------- MFMA split-bf16 GEMM + fused GRU epilogue ----------------

struct KDesc { const unsigned* a; int stride; int pad0; };
struct GArgs { KDesc kd[20]; int nk; };

__global__ __launch_bounds__(256) void mfma_gemm_k(GArgs ga,
    const short* __restrict__ wh0, const short* __restrict__ wl0, const float* __restrict__ bias0,
    const short* __restrict__ wh1, const short* __restrict__ wl1, const float* __restrict__ bias1,
    float* __restrict__ ZR, float* __restrict__ Hf, unsigned* __restrict__ Hp, int epi){
    int tid = threadIdx.x;
    int wv = tid >> 6, lane = tid & 63;
    int rl = lane & 15, kg = lane >> 4;
    int m0 = blockIdx.x*64 + wv*16;
    int gy = blockIdx.y;
    const short* wh = gy ? wh1 : wh0;
    const short* wl = gy ? wl1 : wl0;
    const float* bias = gy ? bias1 : bias0;
    int nk = ga.nk;
    f32x4 acc[4];
    for (int cf=0; cf<4; ++cf){ acc[cf][0]=0.f; acc[cf][1]=0.f; acc[cf][2]=0.f; acc[cf][3]=0.f; }
    for (int ks=0; ks<nk; ++ks){
        const unsigned* pa = ga.kd[ks].a + (size_t)(m0+rl)*(size_t)ga.kd[ks].stride + kg*8;
        uint4 A0 = *(const uint4*)pa;
        uint4 A1 = *(const uint4*)(pa+4);
        bf16x8 ah, al;
        ah[0]=(short)(A0.x & 0xffffu); al[0]=(short)(A0.x >> 16);
        ah[1]=(short)(A0.y & 0xffffu); al[1]=(short)(A0.y >> 16);
        ah[2]=(short)(A0.z & 0xffffu); al[2]=(short)(A0.z >> 16);
        ah[3]=(short)(A0.w & 0xffffu); al[3]=(short)(A0.w >> 16);
        ah[4]=(short)(A1.x & 0xffffu); al[4]=(short)(A1.x >> 16);
        ah[5]=(short)(A1.y & 0xffffu); al[5]=(short)(A1.y >> 16);
        ah[6]=(short)(A1.z & 0xffffu); al[6]=(short)(A1.z >> 16);
        ah[7]=(short)(A1.w & 0xffffu); al[7]=(short)(A1.w >> 16);
        #pragma unroll
        for (int cf=0; cf<4; ++cf){
            size_t wb = ((size_t)(cf*nk + ks)*64 + lane)*8;
            bf16x8 bh = *(const bf16x8*)(wh + wb);
            bf16x8 bl = *(const bf16x8*)(wl + wb);
            acc[cf] = __builtin_amdgcn_mfma_f32_16x16x32_bf16(ah, bh, acc[cf], 0, 0, 0);
            acc[cf] = __builtin_amdgcn_mfma_f32_16x16x32_bf16(al, bh, acc[cf], 0, 0, 0);
            acc[cf] = __builtin_amdgcn_mfma_f32_16x16x32_bf16(ah, bl, acc[cf], 0, 0, 0);
        }
    }
    #pragma unroll
    for (int cf=0; cf<4; ++cf){
        int col = cf*16 + rl;
        float bv = bias[col];
        #pragma unroll
        for (int i=0;i<4;i++){
            int row = m0 + kg*4 + i;
            float v = acc[cf][i] + bv;
            if (epi == 0){
                ZR[(size_t)row*128 + gy*64 + col] = 1.f/(1.f+__expf(-v));
            } else {
                float ht = tanhf(v);
                float z = ZR[(size_t)row*128 + col];
                size_t hx = (size_t)row*64 + col;
                float hold = Hf[hx];
                float hn = z*hold + (1.f-z)*ht;
                Hf[hx] = hn;
                Hp[hx] = packsplit(hn);
            }
        }
    }
}

// ---------------- output projection ----------------
__global__ void proj_k(const float* __restrict__ h1, const float* __restrict__ Wo,
                       const float* __restrict__ bo, float* __restrict__ out, int t){
    int idx = blockIdx.x*blockDim.x + threadIdx.x;
    if (idx >= NB) return;
    int b = idx / NNODES, n = idx - b*NNODES;
    const float* hp = h1 + ((size_t)(n*BATCH + b))*64;
    float s = 0.f;
    #pragma unroll
    for (int j=0;j<64;j+=4){
        float4 hv = *(const float4*)(hp+j);
        float4 wv = *(const float4*)(Wo+j);
        s += hv.x*wv.x + hv.y*wv.y + hv.z*wv.z + hv.w*wv.w;
    }
    out[((size_t)(b*SEQT + t))*NNODES + n] = s + bo[0];
}

// ---------------- launcher ----------------

extern "C" void kernel_launch(void* const* d_in, const int* in_sizes, int n_in,
                              void* d_out, int out_size, void* d_ws, size_t ws_size,
                              hipStream_t stream){
    (void)in_sizes; (void)n_in; (void)out_size; (void)ws_size;
    const float* x  = (const float*)d_in[0];
    const int*   ei = (const int*)d_in[1];
    const float* Wz[2] = {(const float*)d_in[2],  (const float*)d_in[8]};
    const float* bz[2] = {(const float*)d_in[3],  (const float*)d_in[9]};
    const float* Wr[2] = {(const float*)d_in[4],  (const float*)d_in[10]};
    const float* br[2] = {(const float*)d_in[5],  (const float*)d_in[11]};
    const float* Wh[2] = {(const float*)d_in[6],  (const float*)d_in[12]};
    const float* bh[2] = {(const float*)d_in[7],  (const float*)d_in[13]};
    const float* Wo = (const float*)d_in[14];
    const float* bo = (const float*)d_in[15];
    float* out = (float*)d_out;

    char* p = (char*)d_ws;
    auto alloc = [&](size_t bytes)->char*{
        char* r = p; p += (bytes + 255) & ~(size_t)255; return r;
    };
    float*    h0f = (float*)   alloc((size_t)NB*64*4);
    float*    h1f = (float*)   alloc((size_t)NB*64*4);
    unsigned* h0p = (unsigned*)alloc((size_t)NB*64*4);
    unsigned* h1p = (unsigned*)alloc((size_t)NB*64*4);
    float*    ZR  = (float*)   alloc((size_t)NB*128*4);
    unsigned* X1op = (unsigned*)alloc((size_t)NB*128*4);
    unsigned* X1ip = (unsigned*)alloc((size_t)NB*128*4);
    unsigned* X2op = (unsigned*)alloc((size_t)NB*128*4);
    unsigned* X2ip = (unsigned*)alloc((size_t)NB*128*4);
    unsigned* G0p  = (unsigned*)alloc((size_t)NB*64*4);
    unsigned* G1op = (unsigned*)alloc((size_t)NB*64*4);
    unsigned* G1ip = (unsigned*)alloc((size_t)NB*64*4);
    unsigned* G2op = (unsigned*)alloc((size_t)NB*64*4);
    unsigned* G2ip = (unsigned*)alloc((size_t)NB*64*4);
    unsigned* X0L0p = G0p;  // alias: layer0 X0 (NB*96*4 = 15.36MB) lives in G pool (51.2MB), disjoint lifetime
    // weight packs: [layer][gate z,r,h]
    short* wph[2][3]; short* wpl[2][3];
    int NKl[2] = {15, 20};
    for (int l=0;l<2;l++) for (int g=0; g<3; g++){
        size_t sz = (size_t)4*NKl[l]*64*8*2;
        wph[l][g] = (short*)alloc(sz);
        wpl[l][g] = (short*)alloc(sz);
    }
    int* deg_out = (int*)alloc(NNODES*4);
    int* deg_in  = (int*)alloc(NNODES*4);
    int* row_ptr = (int*)alloc((NNODES+1)*4);
    int* cursor  = (int*)alloc(NNODES*4);
    int* csr_src = (int*)alloc(NEDGES*4);
    float* csr_wo = (float*)alloc(NEDGES*4);
    float* csr_wi = (float*)alloc(NEDGES*4);

    hipMemsetAsync(deg_out, 0, NNODES*4, stream);
    hipMemsetAsync(deg_in,  0, NNODES*4, stream);
    hipMemsetAsync(cursor,  0, NNODES*4, stream);
    hipMemsetAsync(h0f, 0, (size_t)NB*64*4, stream);
    hipMemsetAsync(h1f, 0, (size_t)NB*64*4, stream);
    hipMemsetAsync(h0p, 0, (size_t)NB*64*4, stream);
    hipMemsetAsync(h1p, 0, (size_t)NB*64*4, stream);

    count_deg_k<<<(NEDGES+255)/256, 256, 0, stream>>>(ei, deg_out, deg_in);
    scan_k<<<1, 256, 0, stream>>>(deg_in, row_ptr);
    fill_csr_k<<<(NEDGES+255)/256, 256, 0, stream>>>(ei, deg_out, deg_in, row_ptr,
                                                     cursor, csr_src, csr_wo, csr_wi);
    // pack weights (split bf16)
    const float* Wptr[2][3] = {{Wz[0],Wr[0],Wh[0]},{Wz[1],Wr[1],Wh[1]}};
    int Fl[2] = {66, 128}, Fpl[2] = {96, 128};
    for (int l=0;l<2;l++) for (int g=0;g<3;g++){
        int nthr = 4*NKl[l]*64;
        pack_w_k<<<(nthr+255)/256, 256, 0, stream>>>(Wptr[l][g], Fl[l], Fpl[l], NKl[l],
                                                     wph[l][g], wpl[l][g]);
    }

    // K-step descriptor tables (pointers are call-invariant)
    GArgs gaL0; gaL0.nk = 15;
    {
        const unsigned* bl[5] = {X0L0p, X1op, X1ip, X2op, X2ip};
        for (int ks=0; ks<15; ++ks){
            int kb = ks/3, kk = ks - kb*3;
            gaL0.kd[ks].a = bl[kb] + kk*32; gaL0.kd[ks].stride = 96; gaL0.kd[ks].pad0 = 0;
        }
    }
    GArgs gaL1zr; gaL1zr.nk = 20;
    GArgs gaL1h;  gaL1h.nk  = 20;
    {
        const unsigned* s1[4] = {X1op, X1ip, X2op, X2ip};
        const unsigned* gg[4] = {G1op, G1ip, G2op, G2ip};
        for (int ks=0; ks<20; ++ks){
            int kb = ks/4, kk = ks - kb*4;
            if (kb == 0){
                gaL1zr.kd[ks].a = (kk<2) ? (h0p + kk*32) : (h1p + (kk-2)*32);
                gaL1zr.kd[ks].stride = 64;
                gaL1h.kd[ks].a = (kk<2) ? (h0p + kk*32) : (G0p + (kk-2)*32);
                gaL1h.kd[ks].stride = 64;
            } else {
                gaL1zr.kd[ks].a = s1[kb-1] + kk*32;
                gaL1zr.kd[ks].stride = 128;
                if (kk < 2){ gaL1h.kd[ks].a = s1[kb-1] + kk*32; gaL1h.kd[ks].stride = 128; }
                else       { gaL1h.kd[ks].a = gg[kb-1] + (kk-2)*32; gaL1h.kd[ks].stride = 64; }
            }
            gaL1zr.kd[ks].pad0 = 0; gaL1h.kd[ks].pad0 = 0;
        }
    }

    for (int t=0; t<SEQT; ++t){
        // ---------------- layer 0 ----------------
        int n66 = NB*66;
        build_x0_l0_k<false><<<(n66+255)/256,256,0,stream>>>(x, t, h0f, ZR, X0L0p);
        prop_dual_p<66,96,96,false><<<NNODES,256,0,stream>>>(X0L0p, nullptr, X1op, X1ip,
                                                             row_ptr, csr_src, csr_wo, csr_wi);
        prop2_p<66,96,96,96,false><<<dim3(NNODES,2),256,0,stream>>>(X1op, X1ip, X0L0p, nullptr,
                                                             X2op, X2ip, row_ptr, csr_src, csr_wo, csr_wi);
        mfma_gemm_k<<<dim3(625,2),256,0,stream>>>(gaL0, wph[0][0], wpl[0][0], bz[0],
                                                  wph[0][1], wpl[0][1], br[0],
                                                  ZR, nullptr, nullptr, 0);
        build_x0_l0_k<true><<<(n66+255)/256,256,0,stream>>>(x, t, h0f, ZR, X0L0p);
        prop_dual_p<66,96,96,false><<<NNODES,256,0,stream>>>(X0L0p, nullptr, X1op, X1ip,
                                                             row_ptr, csr_src, csr_wo, csr_wi);
        prop2_p<66,96,96,96,false><<<dim3(NNODES,2),256,0,stream>>>(X1op, X1ip, X0L0p, nullptr,
                                                             X2op, X2ip, row_ptr, csr_src, csr_wo, csr_wi);
        mfma_gemm_k<<<dim3(625,1),256,0,stream>>>(gaL0, wph[0][2], wpl[0][2], bh[0],
                                                  nullptr, nullptr, nullptr,
                                                  ZR, h0f, h0p, 1);
        // ---------------- layer 1 ----------------
        prop_dual_p<128,64,128,true><<<NNODES,256,0,stream>>>(h0p, h1p, X1op, X1ip,
                                                             row_ptr, csr_src, csr_wo, csr_wi);
        prop2_p<128,128,128,64,true><<<dim3(NNODES,2),256,0,stream>>>(X1op, X1ip, h0p, h1p,
                                                             X2op, X2ip, row_ptr, csr_src, csr_wo, csr_wi);
        mfma_gemm_k<<<dim3(625,2),256,0,stream>>>(gaL1zr, wph[1][0], wpl[1][0], bz[1],
                                                  wph[1][1], wpl[1][1], br[1],
                                                  ZR, nullptr, nullptr, 0);
        int n64 = NB*64;
        build_g0_k<<<(n64+255)/256,256,0,stream>>>(h1f, ZR, G0p);
        prop_dual_p<64,64,64,false><<<NNODES,256,0,stream>>>(G0p, nullptr, G1op, G1ip,
                                                             row_ptr, csr_src, csr_wo, csr_wi);
        prop2_p<64,64,64,64,false><<<dim3(NNODES,2),256,0,stream>>>(G1op, G1ip, G0p, nullptr,
                                                             G2op, G2ip, row_ptr, csr_src, csr_wo, csr_wi);
        mfma_gemm_k<<<dim3(625,1),256,0,stream>>>(gaL1h, wph[1][2], wpl[1][2], bh[1],
                                                  nullptr, nullptr, nullptr,
                                                  ZR, h1f, h1p, 1);
        proj_k<<<(NB+255)/256,256,0,stream>>>(h1f, Wo, bo, out, t);
    }
}

// Round 3
// 4674.121 us; speedup vs baseline: 1.7337x; 1.2578x over previous
//
#include <hip/hip_runtime.h>
#include <math.h>

#define NNODES 5000
#define NEDGES 50000
#define SEQT 12
#define NB 40000
#define MAXDEG 128

typedef __attribute__((ext_vector_type(8))) short bf16x8;
typedef __attribute__((ext_vector_type(4))) float f32x4;

// ---------- split-bf16 helpers (packed dword: hi bf16 low16, lo bf16 high16) ----------
__device__ __forceinline__ unsigned short f2bf(float f){
    unsigned u = __float_as_uint(f);
    u += 0x7fffu + ((u>>16)&1u);
    return (unsigned short)(u>>16);
}
__device__ __forceinline__ unsigned packsplit(float v){
    unsigned short h = f2bf(v);
    float hf = __uint_as_float(((unsigned)h)<<16);
    unsigned short l = f2bf(v - hf);
    return (unsigned)h | ((unsigned)l<<16);
}
__device__ __forceinline__ float unpackf(unsigned d){
    return __uint_as_float(d<<16) + __uint_as_float(d & 0xffff0000u);
}

// ---------------- setup kernels ----------------

__global__ void count_deg_k(const int* __restrict__ ei, int* deg_out, int* deg_in){
    int e = blockIdx.x*blockDim.x + threadIdx.x;
    if (e < NEDGES){
        atomicAdd(&deg_out[ei[e]], 1);
        atomicAdd(&deg_in[ei[NEDGES + e]], 1);
    }
}

__global__ void scan_k(const int* __restrict__ deg_in, int* __restrict__ row_ptr){
    __shared__ int part[256];
    int tid = threadIdx.x;
    int base = tid*20;
    int loc[20]; int s = 0;
    for (int i=0;i<20;i++){
        int idx = base+i;
        int v = (idx < NNODES) ? deg_in[idx] : 0;
        loc[i] = s; s += v;
    }
    part[tid] = s;
    __syncthreads();
    for (int off=1; off<256; off<<=1){
        int v = (tid>=off) ? part[tid-off] : 0;
        __syncthreads();
        part[tid] += v;
        __syncthreads();
    }
    int prev = (tid==0) ? 0 : part[tid-1];
    for (int i=0;i<20;i++){
        int idx = base+i;
        if (idx < NNODES) row_ptr[idx] = prev + loc[i];
    }
    if (tid==255) row_ptr[NNODES] = part[255];
}

__global__ void fill_csr_k(const int* __restrict__ ei, const int* __restrict__ deg_out,
                           const int* __restrict__ deg_in, const int* __restrict__ row_ptr,
                           int* cursor, int* __restrict__ csr_src,
                           float* __restrict__ csr_wo, float* __restrict__ csr_wi){
    int e = blockIdx.x*blockDim.x + threadIdx.x;
    if (e >= NEDGES) return;
    int s = ei[e], d = ei[NEDGES+e];
    int pos = atomicAdd(&cursor[d], 1);
    int slot = row_ptr[d] + pos;
    csr_src[slot] = s;
    csr_wo[slot] = 1.f/(float)deg_out[s];
    csr_wi[slot] = 1.f/(float)deg_in[d];
}

// pre-pack x for all timesteps: Xtp[t][row][2], row = n*8+b
__global__ void prepack_x_k(const float* __restrict__ x, unsigned* __restrict__ Xtp){
    int idx = blockIdx.x*256 + threadIdx.x;
    if (idx >= SEQT*NB*2) return;
    int tt = idx / (NB*2);
    int r2 = idx - tt*(NB*2);
    int row = r2 >> 1, f = r2 & 1;
    int n = row >> 3, b = row & 7;
    Xtp[idx] = packsplit(x[((size_t)(b*SEQT+tt)*NNODES + n)*2 + f]);
}

// ---------------- weight packing (refolded basis, split bf16, MFMA B-frag layout) ----------------
// refolded basis: {T0, T1o, T1i, U2o=Po T1o, U2i=Pi T1i}
// slot 0: W'0 = W[0,0]+W[1,0]-W[0,2]-W[1,2]; 1: W[0,1]; 2: W[1,1]; 3: 2W[0,2]; 4: 2W[1,2]
__device__ __forceinline__ float wfetch(const float* __restrict__ W, int F, int slot, int f, int c){
    const float* p0 = W + ((size_t)0*F + f)*64 + c;  // (d0,k0)
    const float* p1 = W + ((size_t)1*F + f)*64 + c;  // (d0,k1)
    const float* p2 = W + ((size_t)2*F + f)*64 + c;  // (d0,k2)
    const float* p3 = W + ((size_t)3*F + f)*64 + c;  // (d1,k0)
    const float* p4 = W + ((size_t)4*F + f)*64 + c;  // (d1,k1)
    const float* p5 = W + ((size_t)5*F + f)*64 + c;  // (d1,k2)
    switch(slot){
        case 0: return *p0 + *p3 - *p2 - *p5;
        case 1: return *p1;
        case 2: return *p4;
        case 3: return 2.f * *p2;
        default: return 2.f * *p5;
    }
}

// L0: nk=11. blk0 = XT block: k0-1:W'0[x], 2-3:W1o[x], 4-5:W1i[x], 6-7:W2o'[x], 8-9:W2i'[x], rest 0
//            blk 1+2s, 2+2s (s=0..4): slot s, h-rows f = 2 + (k - (1+2s)*32)
__global__ void pack_l0_k(const float* __restrict__ W, short* __restrict__ wh, short* __restrict__ wl){
    int idx = blockIdx.x*256 + threadIdx.x;
    if (idx >= 4*11*64) return;
    int lane = idx & 63, rest = idx >> 6;
    int ks = rest % 11, cf = rest / 11;
    int col = cf*16 + (lane & 15);
    int kb = ks*32 + ((lane>>4)<<3);
    size_t o = (size_t)idx*8;
    for (int j=0;j<8;j++){
        int k = kb + j;
        float v = 0.f;
        if (ks == 0){
            if (k < 10) v = wfetch(W, 66, k>>1, k&1, col);
        } else {
            int slot = (ks-1)>>1;
            int f = 2 + k - 32 - 64*slot;
            v = wfetch(W, 66, slot, f, col);
        }
        unsigned short hh = f2bf(v);
        float hf = __uint_as_float(((unsigned)hh)<<16);
        wh[o+j] = (short)hh;
        wl[o+j] = (short)f2bf(v - hf);
    }
}

// L1: nk=20: ks 0-3 slot0 f=k; 4-7 slot1; 8-11 slot2; 12-15 slot3; 16-19 slot4; f = k - slot*128
__global__ void pack_l1_k(const float* __restrict__ W, short* __restrict__ wh, short* __restrict__ wl){
    int idx = blockIdx.x*256 + threadIdx.x;
    if (idx >= 4*20*64) return;
    int lane = idx & 63, rest = idx >> 6;
    int ks = rest % 20, cf = rest / 20;
    int col = cf*16 + (lane & 15);
    int kb = ks*32 + ((lane>>4)<<3);
    int slot = ks >> 2;
    size_t o = (size_t)idx*8;
    for (int j=0;j<8;j++){
        int k = kb + j;
        int f = k - slot*128;
        float v = wfetch(W, 128, slot, f, col);
        unsigned short hh = f2bf(v);
        float hf = __uint_as_float(((unsigned)hh)<<16);
        wh[o+j] = (short)hh;
        wl[o+j] = (short)f2bf(v - hf);
    }
}

// ---------------- propagation kernels (16B-granule gathers, CSR by dst) ----------------

// dual prop of a 64-wide packed tensor: Yo = Po S, Yi = Pi S
__global__ __launch_bounds__(128) void k_dual64(
    const unsigned* __restrict__ S,
    unsigned* __restrict__ Yo, unsigned* __restrict__ Yi,
    const int* __restrict__ rp, const int* __restrict__ cs,
    const float* __restrict__ cwo, const float* __restrict__ cwi){
    int n = blockIdx.x;
    int beg = rp[n], deg = rp[n+1]-beg;
    int nst = deg < MAXDEG ? deg : MAXDEG;
    __shared__ int s_o[MAXDEG]; __shared__ float swo[MAXDEG], swi[MAXDEG];
    for (int j=threadIdx.x; j<nst; j+=128){
        s_o[j] = cs[beg+j]*512;
        swo[j] = cwo[beg+j]; swi[j] = cwi[beg+j];
    }
    __syncthreads();
    int c = (threadIdx.x>>4)*64 + (threadIdx.x&15)*4;
    float ao0=0,ao1=0,ao2=0,ao3=0, ai0=0,ai1=0,ai2=0,ai3=0;
    for (int j=0;j<nst;j++){
        uint4 v = *(const uint4*)(S + s_o[j] + c);
        float wo=swo[j], wi=swi[j];
        float x0=unpackf(v.x),x1=unpackf(v.y),x2=unpackf(v.z),x3=unpackf(v.w);
        ao0=fmaf(wo,x0,ao0); ao1=fmaf(wo,x1,ao1); ao2=fmaf(wo,x2,ao2); ao3=fmaf(wo,x3,ao3);
        ai0=fmaf(wi,x0,ai0); ai1=fmaf(wi,x1,ai1); ai2=fmaf(wi,x2,ai2); ai3=fmaf(wi,x3,ai3);
    }
    for (int j=nst;j<deg;j++){
        uint4 v = *(const uint4*)(S + cs[beg+j]*512 + c);
        float wo=cwo[beg+j], wi=cwi[beg+j];
        float x0=unpackf(v.x),x1=unpackf(v.y),x2=unpackf(v.z),x3=unpackf(v.w);
        ao0=fmaf(wo,x0,ao0); ao1=fmaf(wo,x1,ao1); ao2=fmaf(wo,x2,ao2); ao3=fmaf(wo,x3,ao3);
        ai0=fmaf(wi,x0,ai0); ai1=fmaf(wi,x1,ai1); ai2=fmaf(wi,x2,ai2); ai3=fmaf(wi,x3,ai3);
    }
    uint4 po, pi;
    po.x=packsplit(ao0); po.y=packsplit(ao1); po.z=packsplit(ao2); po.w=packsplit(ao3);
    pi.x=packsplit(ai0); pi.y=packsplit(ai1); pi.z=packsplit(ai2); pi.w=packsplit(ai3);
    *(uint4*)(Yo + (size_t)n*512 + c) = po;
    *(uint4*)(Yi + (size_t)n*512 + c) = pi;
}

// U2{sel} = P{sel} T1{sel} for 64-wide tensors (refolded: no X0 term)
__global__ __launch_bounds__(128) void k_prop2_64(
    const unsigned* __restrict__ T1o, const unsigned* __restrict__ T1i,
    unsigned* __restrict__ U2o, unsigned* __restrict__ U2i,
    const int* __restrict__ rp, const int* __restrict__ cs,
    const float* __restrict__ cwo, const float* __restrict__ cwi){
    int n = blockIdx.x, sel = blockIdx.y;
    const unsigned* S = sel ? T1i : T1o;
    unsigned* U = sel ? U2i : U2o;
    const float* cw = sel ? cwi : cwo;
    int beg = rp[n], deg = rp[n+1]-beg;
    int nst = deg < MAXDEG ? deg : MAXDEG;
    __shared__ int s_o[MAXDEG]; __shared__ float s_w[MAXDEG];
    for (int j=threadIdx.x; j<nst; j+=128){
        s_o[j] = cs[beg+j]*512;
        s_w[j] = cw[beg+j];
    }
    __syncthreads();
    int c = (threadIdx.x>>4)*64 + (threadIdx.x&15)*4;
    float a0=0,a1=0,a2=0,a3=0;
    for (int j=0;j<nst;j++){
        uint4 v = *(const uint4*)(S + s_o[j] + c);
        float w=s_w[j];
        a0=fmaf(w,unpackf(v.x),a0); a1=fmaf(w,unpackf(v.y),a1);
        a2=fmaf(w,unpackf(v.z),a2); a3=fmaf(w,unpackf(v.w),a3);
    }
    for (int j=nst;j<deg;j++){
        uint4 v = *(const uint4*)(S + cs[beg+j]*512 + c);
        float w=cw[beg+j];
        a0=fmaf(w,unpackf(v.x),a0); a1=fmaf(w,unpackf(v.y),a1);
        a2=fmaf(w,unpackf(v.z),a2); a3=fmaf(w,unpackf(v.w),a3);
    }
    uint4 p;
    p.x=packsplit(a0); p.y=packsplit(a1); p.z=packsplit(a2); p.w=packsplit(a3);
    *(uint4*)(U + (size_t)n*512 + c) = p;
}

// L0 z/r dual: gathers [Xtp | h0p]; h-part -> T1o/T1i (64-wide); x-part -> XT cols 2-5; copies x_t -> XT cols 0-1
__global__ __launch_bounds__(128) void k_dual_l0zr(
    const unsigned* __restrict__ h0p, const unsigned* __restrict__ Xtp,
    unsigned* __restrict__ T1o, unsigned* __restrict__ T1i, unsigned* __restrict__ XT,
    const int* __restrict__ rp, const int* __restrict__ cs,
    const float* __restrict__ cwo, const float* __restrict__ cwi){
    int n = blockIdx.x;
    int beg = rp[n], deg = rp[n+1]-beg;
    int nst = deg < MAXDEG ? deg : MAXDEG;
    __shared__ int s_o[MAXDEG]; __shared__ float swo[MAXDEG], swi[MAXDEG];
    for (int j=threadIdx.x; j<nst; j+=128){
        s_o[j] = cs[beg+j]*512;
        swo[j] = cwo[beg+j]; swi[j] = cwi[beg+j];
    }
    __syncthreads();
    int c = (threadIdx.x>>4)*64 + (threadIdx.x&15)*4;
    {
        float ao0=0,ao1=0,ao2=0,ao3=0, ai0=0,ai1=0,ai2=0,ai3=0;
        for (int j=0;j<nst;j++){
            uint4 v = *(const uint4*)(h0p + s_o[j] + c);
            float wo=swo[j], wi=swi[j];
            float x0=unpackf(v.x),x1=unpackf(v.y),x2=unpackf(v.z),x3=unpackf(v.w);
            ao0=fmaf(wo,x0,ao0); ao1=fmaf(wo,x1,ao1); ao2=fmaf(wo,x2,ao2); ao3=fmaf(wo,x3,ao3);
            ai0=fmaf(wi,x0,ai0); ai1=fmaf(wi,x1,ai1); ai2=fmaf(wi,x2,ai2); ai3=fmaf(wi,x3,ai3);
        }
        for (int j=nst;j<deg;j++){
            uint4 v = *(const uint4*)(h0p + cs[beg+j]*512 + c);
            float wo=cwo[beg+j], wi=cwi[beg+j];
            float x0=unpackf(v.x),x1=unpackf(v.y),x2=unpackf(v.z),x3=unpackf(v.w);
            ao0=fmaf(wo,x0,ao0); ao1=fmaf(wo,x1,ao1); ao2=fmaf(wo,x2,ao2); ao3=fmaf(wo,x3,ao3);
            ai0=fmaf(wi,x0,ai0); ai1=fmaf(wi,x1,ai1); ai2=fmaf(wi,x2,ai2); ai3=fmaf(wi,x3,ai3);
        }
        uint4 po, pi;
        po.x=packsplit(ao0); po.y=packsplit(ao1); po.z=packsplit(ao2); po.w=packsplit(ao3);
        pi.x=packsplit(ai0); pi.y=packsplit(ai1); pi.z=packsplit(ai2); pi.w=packsplit(ai3);
        *(uint4*)(T1o + (size_t)n*512 + c) = po;
        *(uint4*)(T1i + (size_t)n*512 + c) = pi;
    }
    if (threadIdx.x < 8){
        int b = threadIdx.x;
        float ax0=0,ax1=0, ay0=0,ay1=0;
        for (int j=0;j<nst;j++){
            uint2 v = *(const uint2*)(Xtp + (s_o[j]>>5) + b*2);
            float x0=unpackf(v.x), x1=unpackf(v.y);
            ax0=fmaf(swo[j],x0,ax0); ax1=fmaf(swo[j],x1,ax1);
            ay0=fmaf(swi[j],x0,ay0); ay1=fmaf(swi[j],x1,ay1);
        }
        for (int j=nst;j<deg;j++){
            uint2 v = *(const uint2*)(Xtp + cs[beg+j]*16 + b*2);
            float x0=unpackf(v.x), x1=unpackf(v.y);
            ax0=fmaf(cwo[beg+j],x0,ax0); ax1=fmaf(cwo[beg+j],x1,ax1);
            ay0=fmaf(cwi[beg+j],x0,ay0); ay1=fmaf(cwi[beg+j],x1,ay1);
        }
        size_t ro = ((size_t)n*8 + b)*32;
        size_t xr = ((size_t)n*8 + b)*2;
        XT[ro+0] = Xtp[xr+0]; XT[ro+1] = Xtp[xr+1];
        XT[ro+2] = packsplit(ax0); XT[ro+3] = packsplit(ax1);
        XT[ro+4] = packsplit(ay0); XT[ro+5] = packsplit(ay1);
    }
}

// L0 z/r prop2: h-part U2{sel} = P{sel} T1{sel}h -> T2h; x-part from XT cols (2+2sel) -> XT cols (6+2sel)
__global__ __launch_bounds__(128) void k_prop2_l0zr(
    const unsigned* __restrict__ T1o, const unsigned* __restrict__ T1i,
    unsigned* __restrict__ T2o, unsigned* __restrict__ T2i, unsigned* __restrict__ XT,
    const int* __restrict__ rp, const int* __restrict__ cs,
    const float* __restrict__ cwo, const float* __restrict__ cwi){
    int n = blockIdx.x, sel = blockIdx.y;
    const unsigned* S = sel ? T1i : T1o;
    unsigned* U = sel ? T2i : T2o;
    const float* cw = sel ? cwi : cwo;
    int beg = rp[n], deg = rp[n+1]-beg;
    int nst = deg < MAXDEG ? deg : MAXDEG;
    __shared__ int s_o[MAXDEG]; __shared__ float s_w[MAXDEG];
    for (int j=threadIdx.x; j<nst; j+=128){
        s_o[j] = cs[beg+j]*512;
        s_w[j] = cw[beg+j];
    }
    __syncthreads();
    int c = (threadIdx.x>>4)*64 + (threadIdx.x&15)*4;
    {
        float a0=0,a1=0,a2=0,a3=0;
        for (int j=0;j<nst;j++){
            uint4 v = *(const uint4*)(S + s_o[j] + c);
            float w=s_w[j];
            a0=fmaf(w,unpackf(v.x),a0); a1=fmaf(w,unpackf(v.y),a1);
            a2=fmaf(w,unpackf(v.z),a2); a3=fmaf(w,unpackf(v.w),a3);
        }
        for (int j=nst;j<deg;j++){
            uint4 v = *(const uint4*)(S + cs[beg+j]*512 + c);
            float w=cw[beg+j];
            a0=fmaf(w,unpackf(v.x),a0); a1=fmaf(w,unpackf(v.y),a1);
            a2=fmaf(w,unpackf(v.z),a2); a3=fmaf(w,unpackf(v.w),a3);
        }
        uint4 p;
        p.x=packsplit(a0); p.y=packsplit(a1); p.z=packsplit(a2); p.w=packsplit(a3);
        *(uint4*)(U + (size_t)n*512 + c) = p;
    }
    if (threadIdx.x < 8){
        int b = threadIdx.x;
        int xo = 2 + 2*sel;
        float a0=0,a1=0;
        for (int j=0;j<nst;j++){
            uint2 v = *(const uint2*)(XT + (s_o[j]>>1) + b*32 + xo);
            a0=fmaf(s_w[j],unpackf(v.x),a0); a1=fmaf(s_w[j],unpackf(v.y),a1);
        }
        for (int j=nst;j<deg;j++){
            uint2 v = *(const uint2*)(XT + cs[beg+j]*256 + b*32 + xo);
            a0=fmaf(cw[beg+j],unpackf(v.x),a0); a1=fmaf(cw[beg+j],unpackf(v.y),a1);
        }
        size_t ro = ((size_t)n*8 + b)*32 + 6 + 2*sel;
        XT[ro+0] = packsplit(a0); XT[ro+1] = packsplit(a1);
    }
}

// L1 z/r dual: gathers [h0p | h1p] -> T1o128, T1i128 (128-wide)
__global__ __launch_bounds__(256) void k_dual_2x64(
    const unsigned* __restrict__ h0p, const unsigned* __restrict__ h1p,
    unsigned* __restrict__ T1o, unsigned* __restrict__ T1i,
    const int* __restrict__ rp, const int* __restrict__ cs,
    const float* __restrict__ cwo, const float* __restrict__ cwi){
    int n = blockIdx.x;
    int beg = rp[n], deg = rp[n+1]-beg;
    int nst = deg < MAXDEG ? deg : MAXDEG;
    __shared__ int s_o[MAXDEG]; __shared__ float swo[MAXDEG], swi[MAXDEG];
    for (int j=threadIdx.x; j<nst; j+=256){
        s_o[j] = cs[beg+j]*512;
        swo[j] = cwo[beg+j]; swi[j] = cwi[beg+j];
    }
    __syncthreads();
    int b = threadIdx.x>>5, q = threadIdx.x&31;
    const unsigned* S = (q<16) ? h0p : h1p;
    int c = b*64 + (q&15)*4;
    float ao0=0,ao1=0,ao2=0,ao3=0, ai0=0,ai1=0,ai2=0,ai3=0;
    for (int j=0;j<nst;j++){
        uint4 v = *(const uint4*)(S + s_o[j] + c);
        float wo=swo[j], wi=swi[j];
        float x0=unpackf(v.x),x1=unpackf(v.y),x2=unpackf(v.z),x3=unpackf(v.w);
        ao0=fmaf(wo,x0,ao0); ao1=fmaf(wo,x1,ao1); ao2=fmaf(wo,x2,ao2); ao3=fmaf(wo,x3,ao3);
        ai0=fmaf(wi,x0,ai0); ai1=fmaf(wi,x1,ai1); ai2=fmaf(wi,x2,ai2); ai3=fmaf(wi,x3,ai3);
    }
    for (int j=nst;j<deg;j++){
        uint4 v = *(const uint4*)(S + cs[beg+j]*512 + c);
        float wo=cwo[beg+j], wi=cwi[beg+j];
        float x0=unpackf(v.x),x1=unpackf(v.y),x2=unpackf(v.z),x3=unpackf(v.w);
        ao0=fmaf(wo,x0,ao0); ao1=fmaf(wo,x1,ao1); ao2=fmaf(wo,x2,ao2); ao3=fmaf(wo,x3,ao3);
        ai0=fmaf(wi,x0,ai0); ai1=fmaf(wi,x1,ai1); ai2=fmaf(wi,x2,ai2); ai3=fmaf(wi,x3,ai3);
    }
    uint4 po, pi;
    po.x=packsplit(ao0); po.y=packsplit(ao1); po.z=packsplit(ao2); po.w=packsplit(ao3);
    pi.x=packsplit(ai0); pi.y=packsplit(ai1); pi.z=packsplit(ai2); pi.w=packsplit(ai3);
    size_t o = (size_t)n*1024 + b*128 + q*4;
    *(uint4*)(T1o + o) = po;
    *(uint4*)(T1i + o) = pi;
}

// L1 z/r prop2 on 128-wide tensors
__global__ __launch_bounds__(256) void k_prop2_128(
    const unsigned* __restrict__ T1o, const unsigned* __restrict__ T1i,
    unsigned* __restrict__ U2o, unsigned* __restrict__ U2i,
    const int* __restrict__ rp, const int* __restrict__ cs,
    const float* __restrict__ cwo, const float* __restrict__ cwi){
    int n = blockIdx.x, sel = blockIdx.y;
    const unsigned* S = sel ? T1i : T1o;
    unsigned* U = sel ? U2i : U2o;
    const float* cw = sel ? cwi : cwo;
    int beg = rp[n], deg = rp[n+1]-beg;
    int nst = deg < MAXDEG ? deg : MAXDEG;
    __shared__ int s_o[MAXDEG]; __shared__ float s_w[MAXDEG];
    for (int j=threadIdx.x; j<nst; j+=256){
        s_o[j] = cs[beg+j]*1024;
        s_w[j] = cw[beg+j];
    }
    __syncthreads();
    int b = threadIdx.x>>5, q = threadIdx.x&31;
    int c = b*128 + q*4;
    float a0=0,a1=0,a2=0,a3=0;
    for (int j=0;j<nst;j++){
        uint4 v = *(const uint4*)(S + s_o[j] + c);
        float w=s_w[j];
        a0=fmaf(w,unpackf(v.x),a0); a1=fmaf(w,unpackf(v.y),a1);
        a2=fmaf(w,unpackf(v.z),a2); a3=fmaf(w,unpackf(v.w),a3);
    }
    for (int j=nst;j<deg;j++){
        uint4 v = *(const uint4*)(S + cs[beg+j]*1024 + c);
        float w=cw[beg+j];
        a0=fmaf(w,unpackf(v.x),a0); a1=fmaf(w,unpackf(v.y),a1);
        a2=fmaf(w,unpackf(v.z),a2); a3=fmaf(w,unpackf(v.w),a3);
    }
    uint4 p;
    p.x=packsplit(a0); p.y=packsplit(a1); p.z=packsplit(a2); p.w=packsplit(a3);
    *(uint4*)(U + (size_t)n*1024 + c) = p;
}

// ---------------- MFMA split-bf16 GEMM, fused GRU epilogues ----------------

struct KD { const unsigned* a; int st; };
struct GA { KD kd[20]; };

// EPI 0 (NG=2): z=sig(g0), r=sig(g1); Z[row,col]=z; Gout[row,col]=pack(Hf*r)
// EPI 1 (NG=1): ht=tanh(g0); hn=z*Hf+(1-z)*ht; Hf=hn; Hp=pack(hn)
// EPI 2 (NG=1): EPI1 + fused proj: out[b,t,n] = sum_col hn*Wo[col] + bo
template<int NK, int NG, int EPI>
__global__ __launch_bounds__(256) void k_gemm(GA ga,
    const short* __restrict__ wh0, const short* __restrict__ wl0, const float* __restrict__ b0,
    const short* __restrict__ wh1, const short* __restrict__ wl1, const float* __restrict__ b1,
    float* __restrict__ Z, unsigned* __restrict__ Gout,
    float* __restrict__ Hf, unsigned* __restrict__ Hp,
    const float* __restrict__ Wo, const float* __restrict__ bo,
    float* __restrict__ out, int t){
    int tid = threadIdx.x;
    int lane = tid & 63, wv = tid >> 6, rl = lane & 15, kg = lane >> 4;
    int m0 = blockIdx.x*64 + wv*16;
    f32x4 acc0[4], acc1[4];
    #pragma unroll
    for (int cf=0; cf<4; ++cf){
        acc0[cf][0]=0.f; acc0[cf][1]=0.f; acc0[cf][2]=0.f; acc0[cf][3]=0.f;
        acc1[cf][0]=0.f; acc1[cf][1]=0.f; acc1[cf][2]=0.f; acc1[cf][3]=0.f;
    }
    for (int ks=0; ks<NK; ++ks){
        const unsigned* pa = ga.kd[ks].a + (size_t)(m0+rl)*ga.kd[ks].st + kg*8;
        uint4 A0 = *(const uint4*)pa;
        uint4 A1 = *(const uint4*)(pa+4);
        bf16x8 ah, al;
        ah[0]=(short)(A0.x & 0xffffu); al[0]=(short)(A0.x >> 16);
        ah[1]=(short)(A0.y & 0xffffu); al[1]=(short)(A0.y >> 16);
        ah[2]=(short)(A0.z & 0xffffu); al[2]=(short)(A0.z >> 16);
        ah[3]=(short)(A0.w & 0xffffu); al[3]=(short)(A0.w >> 16);
        ah[4]=(short)(A1.x & 0xffffu); al[4]=(short)(A1.x >> 16);
        ah[5]=(short)(A1.y & 0xffffu); al[5]=(short)(A1.y >> 16);
        ah[6]=(short)(A1.z & 0xffffu); al[6]=(short)(A1.z >> 16);
        ah[7]=(short)(A1.w & 0xffffu); al[7]=(short)(A1.w >> 16);
        #pragma unroll
        for (int cf=0; cf<4; ++cf){
            size_t wb = ((size_t)(cf*NK + ks)*64 + lane)*8;
            bf16x8 bh = *(const bf16x8*)(wh0 + wb);
            bf16x8 bl = *(const bf16x8*)(wl0 + wb);
            acc0[cf] = __builtin_amdgcn_mfma_f32_16x16x32_bf16(ah, bh, acc0[cf], 0, 0, 0);
            acc0[cf] = __builtin_amdgcn_mfma_f32_16x16x32_bf16(al, bh, acc0[cf], 0, 0, 0);
            acc0[cf] = __builtin_amdgcn_mfma_f32_16x16x32_bf16(ah, bl, acc0[cf], 0, 0, 0);
            if (NG == 2){
                bf16x8 ch = *(const bf16x8*)(wh1 + wb);
                bf16x8 cl = *(const bf16x8*)(wl1 + wb);
                acc1[cf] = __builtin_amdgcn_mfma_f32_16x16x32_bf16(ah, ch, acc1[cf], 0, 0, 0);
                acc1[cf] = __builtin_amdgcn_mfma_f32_16x16x32_bf16(al, ch, acc1[cf], 0, 0, 0);
                acc1[cf] = __builtin_amdgcn_mfma_f32_16x16x32_bf16(ah, cl, acc1[cf], 0, 0, 0);
            }
        }
    }
    if (EPI == 0){
        #pragma unroll
        for (int cf=0; cf<4; ++cf){
            int col = cf*16 + rl;
            float bz = b0[col], br = b1[col];
            #pragma unroll
            for (int i=0;i<4;i++){
                int row = m0 + kg*4 + i;
                float z = 1.f/(1.f+__expf(-(acc0[cf][i] + bz)));
                float r = 1.f/(1.f+__expf(-(acc1[cf][i] + br)));
                size_t ix = (size_t)row*64 + col;
                Z[ix] = z;
                Gout[ix] = packsplit(Hf[ix]*r);
            }
        }
    } else {
        float pr[4] = {0.f,0.f,0.f,0.f};
        #pragma unroll
        for (int cf=0; cf<4; ++cf){
            int col = cf*16 + rl;
            float bv = b0[col];
            float wo_c = (EPI == 2) ? Wo[col] : 0.f;
            #pragma unroll
            for (int i=0;i<4;i++){
                int row = m0 + kg*4 + i;
                float ht = tanhf(acc0[cf][i] + bv);
                size_t ix = (size_t)row*64 + col;
                float z = Z[ix];
                float hn = z*Hf[ix] + (1.f-z)*ht;
                Hf[ix] = hn;
                Hp[ix] = packsplit(hn);
                if (EPI == 2) pr[i] = fmaf(hn, wo_c, pr[i]);
            }
        }
        if (EPI == 2){
            #pragma unroll
            for (int i=0;i<4;i++){
                pr[i] += __shfl_xor(pr[i], 1);
                pr[i] += __shfl_xor(pr[i], 2);
                pr[i] += __shfl_xor(pr[i], 4);
                pr[i] += __shfl_xor(pr[i], 8);
            }
            if (rl == 0){
                float bb = bo[0];
                #pragma unroll
                for (int i=0;i<4;i++){
                    int row = m0 + kg*4 + i;
                    int n = row >> 3, b = row & 7;
                    out[(size_t)(b*SEQT + t)*NNODES + n] = pr[i] + bb;
                }
            }
        }
    }
}

// ---------------- launcher ----------------

extern "C" void kernel_launch(void* const* d_in, const int* in_sizes, int n_in,
                              void* d_out, int out_size, void* d_ws, size_t ws_size,
                              hipStream_t stream){
    (void)in_sizes; (void)n_in; (void)out_size; (void)ws_size;
    const float* x  = (const float*)d_in[0];
    const int*   ei = (const int*)d_in[1];
    const float* Wz[2] = {(const float*)d_in[2],  (const float*)d_in[8]};
    const float* bz[2] = {(const float*)d_in[3],  (const float*)d_in[9]};
    const float* Wr[2] = {(const float*)d_in[4],  (const float*)d_in[10]};
    const float* br[2] = {(const float*)d_in[5],  (const float*)d_in[11]};
    const float* Wh[2] = {(const float*)d_in[6],  (const float*)d_in[12]};
    const float* bh[2] = {(const float*)d_in[7],  (const float*)d_in[13]};
    const float* Wo = (const float*)d_in[14];
    const float* bo = (const float*)d_in[15];
    float* out = (float*)d_out;

    char* p = (char*)d_ws;
    auto alloc = [&](size_t bytes)->char*{
        char* r = p; p += (bytes + 255) & ~(size_t)255; return r;
    };
    const size_t SZ64  = (size_t)NB*64*4;    // 10.24 MB
    const size_t SZ128 = (size_t)NB*128*4;   // 20.48 MB
    unsigned* Xtp = (unsigned*)alloc((size_t)SEQT*NB*2*4);
    float*    h0f = (float*)   alloc(SZ64);
    float*    h1f = (float*)   alloc(SZ64);
    unsigned* h0p = (unsigned*)alloc(SZ64);
    unsigned* h1p = (unsigned*)alloc(SZ64);
    float*    Z0  = (float*)   alloc(SZ64);
    float*    Z1  = (float*)   alloc(SZ64);
    unsigned* XT  = (unsigned*)alloc((size_t)NB*32*4);  // 5.12 MB
    // shared region: L0 tensors (Th 4x + G_l0 5x) overlap L1's T128 4x; G_l1 placed after T128
    char* R = alloc(4*SZ128 + 5*SZ64);       // 133.1 MB
    unsigned* Th1o = (unsigned*)(R + 0*SZ64);
    unsigned* Th1i = (unsigned*)(R + 1*SZ64);
    unsigned* Th2o = (unsigned*)(R + 2*SZ64);
    unsigned* Th2i = (unsigned*)(R + 3*SZ64);
    unsigned* G0L0 = (unsigned*)(R + 4*SZ64);
    unsigned* G1o0 = (unsigned*)(R + 5*SZ64);
    unsigned* G1i0 = (unsigned*)(R + 6*SZ64);
    unsigned* G2o0 = (unsigned*)(R + 7*SZ64);
    unsigned* G2i0 = (unsigned*)(R + 8*SZ64);
    unsigned* T1o128 = (unsigned*)(R + 0*SZ128);
    unsigned* T1i128 = (unsigned*)(R + 1*SZ128);
    unsigned* U2o128 = (unsigned*)(R + 2*SZ128);
    unsigned* U2i128 = (unsigned*)(R + 3*SZ128);
    unsigned* G0p  = (unsigned*)(R + 4*SZ128 + 0*SZ64);
    unsigned* G1o1 = (unsigned*)(R + 4*SZ128 + 1*SZ64);
    unsigned* G1i1 = (unsigned*)(R + 4*SZ128 + 2*SZ64);
    unsigned* G2o1 = (unsigned*)(R + 4*SZ128 + 3*SZ64);
    unsigned* G2i1 = (unsigned*)(R + 4*SZ128 + 4*SZ64);
    // weight packs
    short *whl0[3][2], *whl1[3][2];
    for (int g=0; g<3; ++g){
        whl0[g][0] = (short*)alloc((size_t)4*11*64*8*2);
        whl0[g][1] = (short*)alloc((size_t)4*11*64*8*2);
        whl1[g][0] = (short*)alloc((size_t)4*20*64*8*2);
        whl1[g][1] = (short*)alloc((size_t)4*20*64*8*2);
    }
    int* deg_out = (int*)alloc(NNODES*4);
    int* deg_in  = (int*)alloc(NNODES*4);
    int* row_ptr = (int*)alloc((NNODES+1)*4);
    int* cursor  = (int*)alloc(NNODES*4);
    int* csr_src = (int*)alloc(NEDGES*4);
    float* csr_wo = (float*)alloc(NEDGES*4);
    float* csr_wi = (float*)alloc(NEDGES*4);

    hipMemsetAsync(deg_out, 0, NNODES*4, stream);
    hipMemsetAsync(deg_in,  0, NNODES*4, stream);
    hipMemsetAsync(cursor,  0, NNODES*4, stream);
    hipMemsetAsync(h0f, 0, SZ64, stream);
    hipMemsetAsync(h1f, 0, SZ64, stream);
    hipMemsetAsync(h0p, 0, SZ64, stream);
    hipMemsetAsync(h1p, 0, SZ64, stream);
    hipMemsetAsync(XT,  0, (size_t)NB*32*4, stream);

    count_deg_k<<<(NEDGES+255)/256, 256, 0, stream>>>(ei, deg_out, deg_in);
    scan_k<<<1, 256, 0, stream>>>(deg_in, row_ptr);
    fill_csr_k<<<(NEDGES+255)/256, 256, 0, stream>>>(ei, deg_out, deg_in, row_ptr,
                                                     cursor, csr_src, csr_wo, csr_wi);
    prepack_x_k<<<(SEQT*NB*2+255)/256, 256, 0, stream>>>(x, Xtp);
    const float* Wptr0[3] = {Wz[0], Wr[0], Wh[0]};
    const float* Wptr1[3] = {Wz[1], Wr[1], Wh[1]};
    for (int g=0; g<3; ++g){
        pack_l0_k<<<(4*11*64+255)/256, 256, 0, stream>>>(Wptr0[g], whl0[g][0], whl0[g][1]);
        pack_l1_k<<<(4*20*64+255)/256, 256, 0, stream>>>(Wptr1[g], whl1[g][0], whl1[g][1]);
    }

    // GEMM K-block descriptor tables
    GA gaL0zr = {}, gaL0h = {}, gaL1zr = {}, gaL1h = {};
    {
        // L0 z/r: blk0 XT; 1-2 h0p; 3-4 Th1o; 5-6 Th1i; 7-8 Th2o; 9-10 Th2i
        const unsigned* t64[5] = {h0p, Th1o, Th1i, Th2o, Th2i};
        gaL0zr.kd[0] = {XT, 32};
        for (int s=0; s<5; ++s){
            gaL0zr.kd[1+2*s] = {t64[s], 64};
            gaL0zr.kd[2+2*s] = {t64[s]+32, 64};
        }
        const unsigned* g64[5] = {G0L0, G1o0, G1i0, G2o0, G2i0};
        gaL0h.kd[0] = {XT, 32};
        for (int s=0; s<5; ++s){
            gaL0h.kd[1+2*s] = {g64[s], 64};
            gaL0h.kd[2+2*s] = {g64[s]+32, 64};
        }
        // L1 z/r: 0-1 h0p; 2-3 h1p; 4-7 T1o128; 8-11 T1i128; 12-15 U2o128; 16-19 U2i128
        gaL1zr.kd[0] = {h0p, 64};    gaL1zr.kd[1] = {h0p+32, 64};
        gaL1zr.kd[2] = {h1p, 64};    gaL1zr.kd[3] = {h1p+32, 64};
        const unsigned* t128[4] = {T1o128, T1i128, U2o128, U2i128};
        for (int s=0; s<4; ++s)
            for (int q=0; q<4; ++q)
                gaL1zr.kd[4+4*s+q] = {t128[s]+32*q, 128};
        // L1 h: 0-1 h0p; 2-3 G0p; 4-5 T1o128[0:64]; 6-7 G1o1; 8-9 T1i128[0:64]; 10-11 G1i1;
        //       12-13 U2o128[0:64]; 14-15 G2o1; 16-17 U2i128[0:64]; 18-19 G2i1
        gaL1h.kd[0] = {h0p, 64};  gaL1h.kd[1] = {h0p+32, 64};
        gaL1h.kd[2] = {G0p, 64};  gaL1h.kd[3] = {G0p+32, 64};
        const unsigned* gh[4] = {G1o1, G1i1, G2o1, G2i1};
        for (int s=0; s<4; ++s){
            gaL1h.kd[4+4*s+0] = {t128[s], 128};
            gaL1h.kd[4+4*s+1] = {t128[s]+32, 128};
            gaL1h.kd[4+4*s+2] = {gh[s], 64};
            gaL1h.kd[4+4*s+3] = {gh[s]+32, 64};
        }
    }

    for (int t=0; t<SEQT; ++t){
        // ---- layer 0 ----
        k_dual_l0zr<<<NNODES, 128, 0, stream>>>(h0p, Xtp + (size_t)t*NB*2, Th1o, Th1i, XT,
                                                row_ptr, csr_src, csr_wo, csr_wi);
        k_prop2_l0zr<<<dim3(NNODES,2), 128, 0, stream>>>(Th1o, Th1i, Th2o, Th2i, XT,
                                                row_ptr, csr_src, csr_wo, csr_wi);
        k_gemm<11,2,0><<<NB/64, 256, 0, stream>>>(gaL0zr,
            whl0[0][0], whl0[0][1], bz[0], whl0[1][0], whl0[1][1], br[0],
            Z0, G0L0, h0f, nullptr, nullptr, nullptr, nullptr, 0);
        k_dual64<<<NNODES, 128, 0, stream>>>(G0L0, G1o0, G1i0, row_ptr, csr_src, csr_wo, csr_wi);
        k_prop2_64<<<dim3(NNODES,2), 128, 0, stream>>>(G1o0, G1i0, G2o0, G2i0,
                                                row_ptr, csr_src, csr_wo, csr_wi);
        k_gemm<11,1,1><<<NB/64, 256, 0, stream>>>(gaL0h,
            whl0[2][0], whl0[2][1], bh[0], nullptr, nullptr, nullptr,
            Z0, nullptr, h0f, h0p, nullptr, nullptr, nullptr, 0);
        // ---- layer 1 ----
        k_dual_2x64<<<NNODES, 256, 0, stream>>>(h0p, h1p, T1o128, T1i128,
                                                row_ptr, csr_src, csr_wo, csr_wi);
        k_prop2_128<<<dim3(NNODES,2), 256, 0, stream>>>(T1o128, T1i128, U2o128, U2i128,
                                                row_ptr, csr_src, csr_wo, csr_wi);
        k_gemm<20,2,0><<<NB/64, 256, 0, stream>>>(gaL1zr,
            whl1[0][0], whl1[0][1], bz[1], whl1[1][0], whl1[1][1], br[1],
            Z1, G0p, h1f, nullptr, nullptr, nullptr, nullptr, 0);
        k_dual64<<<NNODES, 128, 0, stream>>>(G0p, G1o1, G1i1, row_ptr, csr_src, csr_wo, csr_wi);
        k_prop2_64<<<dim3(NNODES,2), 128, 0, stream>>>(G1o1, G1i1, G2o1, G2i1,
                                                row_ptr, csr_src, csr_wo, csr_wi);
        k_gemm<20,1,2><<<NB/64, 256, 0, stream>>>(gaL1h,
            whl1[2][0], whl1[2][1], bh[1], nullptr, nullptr, nullptr,
            Z1, nullptr, h1f, h1p, Wo, bo, out, t);
    }
}

// Round 4
// 3224.476 us; speedup vs baseline: 2.5131x; 1.4496x over previous
//
#include <hip/hip_runtime.h>
#include <math.h>

#define NNODES 5000
#define NEDGES 50000
#define SEQT 12
#define NB 40000
#define MAXDEG 128

typedef __attribute__((ext_vector_type(8))) _Float16 half8;
typedef __attribute__((ext_vector_type(2))) _Float16 half2v;
typedef __attribute__((ext_vector_type(4))) float f32x4;

// ---------------- setup kernels ----------------

__global__ void count_deg_k(const int* __restrict__ ei, int* deg_out, int* deg_in){
    int e = blockIdx.x*blockDim.x + threadIdx.x;
    if (e < NEDGES){
        atomicAdd(&deg_out[ei[e]], 1);
        atomicAdd(&deg_in[ei[NEDGES + e]], 1);
    }
}

__global__ void scan_k(const int* __restrict__ deg_in, int* __restrict__ row_ptr){
    __shared__ int part[256];
    int tid = threadIdx.x;
    int base = tid*20;
    int loc[20]; int s = 0;
    for (int i=0;i<20;i++){
        int idx = base+i;
        int v = (idx < NNODES) ? deg_in[idx] : 0;
        loc[i] = s; s += v;
    }
    part[tid] = s;
    __syncthreads();
    for (int off=1; off<256; off<<=1){
        int v = (tid>=off) ? part[tid-off] : 0;
        __syncthreads();
        part[tid] += v;
        __syncthreads();
    }
    int prev = (tid==0) ? 0 : part[tid-1];
    for (int i=0;i<20;i++){
        int idx = base+i;
        if (idx < NNODES) row_ptr[idx] = prev + loc[i];
    }
    if (tid==255) row_ptr[NNODES] = part[255];
}

__global__ void fill_csr_k(const int* __restrict__ ei, const int* __restrict__ deg_out,
                           const int* __restrict__ deg_in, const int* __restrict__ row_ptr,
                           int* cursor, int* __restrict__ csr_src,
                           float* __restrict__ csr_wo, float* __restrict__ csr_wi){
    int e = blockIdx.x*blockDim.x + threadIdx.x;
    if (e >= NEDGES) return;
    int s = ei[e], d = ei[NEDGES+e];
    int pos = atomicAdd(&cursor[d], 1);
    int slot = row_ptr[d] + pos;
    csr_src[slot] = s;
    csr_wo[slot] = 1.f/(float)deg_out[s];
    csr_wi[slot] = 1.f/(float)deg_in[d];
}

// pre-pack x for all timesteps: Xtph[t][row][2] fp16, row = n*8+b
__global__ void prepack_x_k(const float* __restrict__ x, _Float16* __restrict__ Xtph){
    int idx = blockIdx.x*256 + threadIdx.x;
    if (idx >= SEQT*NB*2) return;
    int tt = idx / (NB*2);
    int r2 = idx - tt*(NB*2);
    int row = r2 >> 1, f = r2 & 1;
    int n = row >> 3, b = row & 7;
    Xtph[idx] = (_Float16)x[((size_t)(b*SEQT+tt)*NNODES + n)*2 + f];
}

// ---------------- weight packing (refolded basis, split fp16, MFMA B-frag layout) ----------------
// refolded basis: {T0, T1o, T1i, U2o=Po T1o, U2i=Pi T1i}
// slot 0: W'0 = W[0,0]+W[1,0]-W[0,2]-W[1,2]; 1: W[0,1]; 2: W[1,1]; 3: 2W[0,2]; 4: 2W[1,2]
__device__ __forceinline__ float wfetch(const float* __restrict__ W, int F, int slot, int f, int c){
    const float* p0 = W + ((size_t)0*F + f)*64 + c;
    const float* p1 = W + ((size_t)1*F + f)*64 + c;
    const float* p2 = W + ((size_t)2*F + f)*64 + c;
    const float* p3 = W + ((size_t)3*F + f)*64 + c;
    const float* p4 = W + ((size_t)4*F + f)*64 + c;
    const float* p5 = W + ((size_t)5*F + f)*64 + c;
    switch(slot){
        case 0: return *p0 + *p3 - *p2 - *p5;
        case 1: return *p1;
        case 2: return *p4;
        case 3: return 2.f * *p2;
        default: return 2.f * *p5;
    }
}

// L0: nk=11. blk0 = XT block: k0-1:slot0[x], 2-3:slot1[x], 4-5:slot2[x], 6-7:slot3[x], 8-9:slot4[x], rest 0
//            blk 1+2s, 2+2s (s=0..4): slot s, h-rows f = 2 + (k - (1+2s)*32)
__global__ void pack_l0_k(const float* __restrict__ W, _Float16* __restrict__ wh, _Float16* __restrict__ wl){
    int idx = blockIdx.x*256 + threadIdx.x;
    if (idx >= 4*11*64) return;
    int lane = idx & 63, rest = idx >> 6;
    int ks = rest % 11, cf = rest / 11;
    int col = cf*16 + (lane & 15);
    int kb = ks*32 + ((lane>>4)<<3);
    size_t o = (size_t)idx*8;
    for (int j=0;j<8;j++){
        int k = kb + j;
        float v = 0.f;
        if (ks == 0){
            if (k < 10) v = wfetch(W, 66, k>>1, k&1, col);
        } else {
            int slot = (ks-1)>>1;
            int f = 2 + k - 32 - 64*slot;
            v = wfetch(W, 66, slot, f, col);
        }
        _Float16 hh = (_Float16)v;
        wh[o+j] = hh;
        wl[o+j] = (_Float16)(v - (float)hh);
    }
}

// L1: nk=20: ks>>2 = slot; f = k - slot*128
__global__ void pack_l1_k(const float* __restrict__ W, _Float16* __restrict__ wh, _Float16* __restrict__ wl){
    int idx = blockIdx.x*256 + threadIdx.x;
    if (idx >= 4*20*64) return;
    int lane = idx & 63, rest = idx >> 6;
    int ks = rest % 20, cf = rest / 20;
    int col = cf*16 + (lane & 15);
    int kb = ks*32 + ((lane>>4)<<3);
    int slot = ks >> 2;
    size_t o = (size_t)idx*8;
    for (int j=0;j<8;j++){
        int k = kb + j;
        int f = k - slot*128;
        float v = wfetch(W, 128, slot, f, col);
        _Float16 hh = (_Float16)v;
        wh[o+j] = hh;
        wl[o+j] = (_Float16)(v - (float)hh);
    }
}

// ---------------- propagation kernels (fp16, 16B-granule gathers, CSR by dst) ----------------

// dual prop of a WH-wide fp16 tensor: Yo = Po S, Yi = Pi S (shared gather)
template<int WH>
__global__ __launch_bounds__(WH) void k_dualh(
    const _Float16* __restrict__ S,
    _Float16* __restrict__ Yo, _Float16* __restrict__ Yi,
    const int* __restrict__ rp, const int* __restrict__ cs,
    const float* __restrict__ cwo, const float* __restrict__ cwi){
    constexpr int SLAB = 8*WH;
    int n = blockIdx.x;
    int beg = rp[n], deg = rp[n+1]-beg;
    int nst = deg < MAXDEG ? deg : MAXDEG;
    __shared__ int s_o[MAXDEG]; __shared__ float swo[MAXDEG], swi[MAXDEG];
    for (int j=threadIdx.x; j<nst; j+=WH){
        s_o[j] = cs[beg+j]*SLAB;
        swo[j] = cwo[beg+j]; swi[j] = cwi[beg+j];
    }
    __syncthreads();
    int off = threadIdx.x*8;
    float ao[8] = {0,0,0,0,0,0,0,0}, ai[8] = {0,0,0,0,0,0,0,0};
    for (int j=0;j<nst;j++){
        half8 v = *(const half8*)(S + s_o[j] + off);
        float wo=swo[j], wi=swi[j];
        #pragma unroll
        for (int e=0;e<8;e++){
            float xv = (float)v[e];
            ao[e]=fmaf(wo,xv,ao[e]); ai[e]=fmaf(wi,xv,ai[e]);
        }
    }
    for (int j=nst;j<deg;j++){
        half8 v = *(const half8*)(S + (size_t)cs[beg+j]*SLAB + off);
        float wo=cwo[beg+j], wi=cwi[beg+j];
        #pragma unroll
        for (int e=0;e<8;e++){
            float xv = (float)v[e];
            ao[e]=fmaf(wo,xv,ao[e]); ai[e]=fmaf(wi,xv,ai[e]);
        }
    }
    half8 po, pi;
    #pragma unroll
    for (int e=0;e<8;e++){ po[e]=(_Float16)ao[e]; pi[e]=(_Float16)ai[e]; }
    *(half8*)(Yo + (size_t)n*SLAB + off) = po;
    *(half8*)(Yi + (size_t)n*SLAB + off) = pi;
}

// second hop: U2{sel} = P{sel} T1{sel}; 1-D grid, sel = bx&1 (XCD-parity split)
template<int WH>
__global__ __launch_bounds__(WH) void k_prop2h(
    const _Float16* __restrict__ T1o, const _Float16* __restrict__ T1i,
    _Float16* __restrict__ U2o, _Float16* __restrict__ U2i,
    const int* __restrict__ rp, const int* __restrict__ cs,
    const float* __restrict__ cwo, const float* __restrict__ cwi){
    constexpr int SLAB = 8*WH;
    int bx = blockIdx.x;
    int n = bx >> 1, sel = bx & 1;
    const _Float16* S = sel ? T1i : T1o;
    _Float16* U = sel ? U2i : U2o;
    const float* cw = sel ? cwi : cwo;
    int beg = rp[n], deg = rp[n+1]-beg;
    int nst = deg < MAXDEG ? deg : MAXDEG;
    __shared__ int s_o[MAXDEG]; __shared__ float s_w[MAXDEG];
    for (int j=threadIdx.x; j<nst; j+=WH){
        s_o[j] = cs[beg+j]*SLAB;
        s_w[j] = cw[beg+j];
    }
    __syncthreads();
    int off = threadIdx.x*8;
    float a[8] = {0,0,0,0,0,0,0,0};
    for (int j=0;j<nst;j++){
        half8 v = *(const half8*)(S + s_o[j] + off);
        float w=s_w[j];
        #pragma unroll
        for (int e=0;e<8;e++) a[e]=fmaf(w,(float)v[e],a[e]);
    }
    for (int j=nst;j<deg;j++){
        half8 v = *(const half8*)(S + (size_t)cs[beg+j]*SLAB + off);
        float w=cw[beg+j];
        #pragma unroll
        for (int e=0;e<8;e++) a[e]=fmaf(w,(float)v[e],a[e]);
    }
    half8 p;
    #pragma unroll
    for (int e=0;e<8;e++) p[e]=(_Float16)a[e];
    *(half8*)(U + (size_t)n*SLAB + off) = p;
}

// L0 first hop: gathers h0h + x; h-part -> Th1o/Th1i; x-part -> XTh cols 2-5; copies x -> cols 0-1
__global__ __launch_bounds__(64) void k_dual_l0zrh(
    const _Float16* __restrict__ h0h, const _Float16* __restrict__ Xt,
    _Float16* __restrict__ T1o, _Float16* __restrict__ T1i, _Float16* __restrict__ XTh,
    const int* __restrict__ rp, const int* __restrict__ cs,
    const float* __restrict__ cwo, const float* __restrict__ cwi){
    int n = blockIdx.x;
    int beg = rp[n], deg = rp[n+1]-beg;
    int nst = deg < MAXDEG ? deg : MAXDEG;
    __shared__ int s_o[MAXDEG]; __shared__ float swo[MAXDEG], swi[MAXDEG];
    for (int j=threadIdx.x; j<nst; j+=64){
        s_o[j] = cs[beg+j]*512;
        swo[j] = cwo[beg+j]; swi[j] = cwi[beg+j];
    }
    __syncthreads();
    int off = threadIdx.x*8;
    {
        float ao[8] = {0,0,0,0,0,0,0,0}, ai[8] = {0,0,0,0,0,0,0,0};
        for (int j=0;j<nst;j++){
            half8 v = *(const half8*)(h0h + s_o[j] + off);
            float wo=swo[j], wi=swi[j];
            #pragma unroll
            for (int e=0;e<8;e++){
                float xv = (float)v[e];
                ao[e]=fmaf(wo,xv,ao[e]); ai[e]=fmaf(wi,xv,ai[e]);
            }
        }
        for (int j=nst;j<deg;j++){
            half8 v = *(const half8*)(h0h + (size_t)cs[beg+j]*512 + off);
            float wo=cwo[beg+j], wi=cwi[beg+j];
            #pragma unroll
            for (int e=0;e<8;e++){
                float xv = (float)v[e];
                ao[e]=fmaf(wo,xv,ao[e]); ai[e]=fmaf(wi,xv,ai[e]);
            }
        }
        half8 po, pi;
        #pragma unroll
        for (int e=0;e<8;e++){ po[e]=(_Float16)ao[e]; pi[e]=(_Float16)ai[e]; }
        *(half8*)(T1o + (size_t)n*512 + off) = po;
        *(half8*)(T1i + (size_t)n*512 + off) = pi;
    }
    if (threadIdx.x < 8){
        int b = threadIdx.x;
        float ax0=0,ax1=0, ay0=0,ay1=0;
        for (int j=0;j<nst;j++){
            int src = s_o[j] >> 9;
            half2v v = *(const half2v*)(Xt + src*16 + b*2);
            float x0=(float)v[0], x1=(float)v[1];
            ax0=fmaf(swo[j],x0,ax0); ax1=fmaf(swo[j],x1,ax1);
            ay0=fmaf(swi[j],x0,ay0); ay1=fmaf(swi[j],x1,ay1);
        }
        for (int j=nst;j<deg;j++){
            int src = cs[beg+j];
            half2v v = *(const half2v*)(Xt + src*16 + b*2);
            float x0=(float)v[0], x1=(float)v[1];
            ax0=fmaf(cwo[beg+j],x0,ax0); ax1=fmaf(cwo[beg+j],x1,ax1);
            ay0=fmaf(cwi[beg+j],x0,ay0); ay1=fmaf(cwi[beg+j],x1,ay1);
        }
        size_t ro = (size_t)(n*8 + b)*32;
        XTh[ro+0] = Xt[(size_t)(n*8+b)*2+0];
        XTh[ro+1] = Xt[(size_t)(n*8+b)*2+1];
        XTh[ro+2] = (_Float16)ax0; XTh[ro+3] = (_Float16)ax1;
        XTh[ro+4] = (_Float16)ay0; XTh[ro+5] = (_Float16)ay1;
    }
}

// L0 second hop: h-part Th2{sel} = P{sel} Th1{sel}; x-part XTh cols (2+2sel) -> (6+2sel)
__global__ __launch_bounds__(64) void k_prop2_l0zrh(
    const _Float16* __restrict__ T1o, const _Float16* __restrict__ T1i,
    _Float16* __restrict__ T2o, _Float16* __restrict__ T2i, _Float16* __restrict__ XTh,
    const int* __restrict__ rp, const int* __restrict__ cs,
    const float* __restrict__ cwo, const float* __restrict__ cwi){
    int bx = blockIdx.x;
    int n = bx >> 1, sel = bx & 1;
    const _Float16* S = sel ? T1i : T1o;
    _Float16* U = sel ? T2i : T2o;
    const float* cw = sel ? cwi : cwo;
    int beg = rp[n], deg = rp[n+1]-beg;
    int nst = deg < MAXDEG ? deg : MAXDEG;
    __shared__ int s_o[MAXDEG]; __shared__ float s_w[MAXDEG];
    for (int j=threadIdx.x; j<nst; j+=64){
        s_o[j] = cs[beg+j]*512;
        s_w[j] = cw[beg+j];
    }
    __syncthreads();
    int off = threadIdx.x*8;
    {
        float a[8] = {0,0,0,0,0,0,0,0};
        for (int j=0;j<nst;j++){
            half8 v = *(const half8*)(S + s_o[j] + off);
            float w=s_w[j];
            #pragma unroll
            for (int e=0;e<8;e++) a[e]=fmaf(w,(float)v[e],a[e]);
        }
        for (int j=nst;j<deg;j++){
            half8 v = *(const half8*)(S + (size_t)cs[beg+j]*512 + off);
            float w=cw[beg+j];
            #pragma unroll
            for (int e=0;e<8;e++) a[e]=fmaf(w,(float)v[e],a[e]);
        }
        half8 p;
        #pragma unroll
        for (int e=0;e<8;e++) p[e]=(_Float16)a[e];
        *(half8*)(U + (size_t)n*512 + off) = p;
    }
    if (threadIdx.x < 8){
        int b = threadIdx.x;
        int xo = 2 + 2*sel;
        float a0=0,a1=0;
        for (int j=0;j<nst;j++){
            int src = s_o[j] >> 9;
            half2v v = *(const half2v*)(XTh + (size_t)src*256 + b*32 + xo);
            a0=fmaf(s_w[j],(float)v[0],a0); a1=fmaf(s_w[j],(float)v[1],a1);
        }
        for (int j=nst;j<deg;j++){
            int src = cs[beg+j];
            half2v v = *(const half2v*)(XTh + (size_t)src*256 + b*32 + xo);
            a0=fmaf(cw[beg+j],(float)v[0],a0); a1=fmaf(cw[beg+j],(float)v[1],a1);
        }
        size_t ro = (size_t)(n*8 + b)*32 + 6 + 2*sel;
        XTh[ro+0] = (_Float16)a0; XTh[ro+1] = (_Float16)a1;
    }
}

// L1 first hop: gathers [h0h | h1h] -> T1o128/T1i128 (128-wide)
__global__ __launch_bounds__(128) void k_dual2x64h(
    const _Float16* __restrict__ h0h, const _Float16* __restrict__ h1h,
    _Float16* __restrict__ T1o, _Float16* __restrict__ T1i,
    const int* __restrict__ rp, const int* __restrict__ cs,
    const float* __restrict__ cwo, const float* __restrict__ cwi){
    int n = blockIdx.x;
    int beg = rp[n], deg = rp[n+1]-beg;
    int nst = deg < MAXDEG ? deg : MAXDEG;
    __shared__ int s_o[MAXDEG]; __shared__ float swo[MAXDEG], swi[MAXDEG];
    for (int j=threadIdx.x; j<nst; j+=128){
        s_o[j] = cs[beg+j]*512;
        swo[j] = cwo[beg+j]; swi[j] = cwi[beg+j];
    }
    __syncthreads();
    int off = threadIdx.x*8;            // within 1024-half output slab
    int b = off >> 7, c = off & 127;
    const _Float16* S = (c < 64) ? h0h : h1h;
    int soff = b*64 + (c & 63);
    float ao[8] = {0,0,0,0,0,0,0,0}, ai[8] = {0,0,0,0,0,0,0,0};
    for (int j=0;j<nst;j++){
        half8 v = *(const half8*)(S + s_o[j] + soff);
        float wo=swo[j], wi=swi[j];
        #pragma unroll
        for (int e=0;e<8;e++){
            float xv = (float)v[e];
            ao[e]=fmaf(wo,xv,ao[e]); ai[e]=fmaf(wi,xv,ai[e]);
        }
    }
    for (int j=nst;j<deg;j++){
        half8 v = *(const half8*)(S + (size_t)cs[beg+j]*512 + soff);
        float wo=cwo[beg+j], wi=cwi[beg+j];
        #pragma unroll
        for (int e=0;e<8;e++){
            float xv = (float)v[e];
            ao[e]=fmaf(wo,xv,ao[e]); ai[e]=fmaf(wi,xv,ai[e]);
        }
    }
    half8 po, pi;
    #pragma unroll
    for (int e=0;e<8;e++){ po[e]=(_Float16)ao[e]; pi[e]=(_Float16)ai[e]; }
    *(half8*)(T1o + (size_t)n*1024 + off) = po;
    *(half8*)(T1i + (size_t)n*1024 + off) = pi;
}

// ---------------- MFMA f16 GEMM (split-f16 weights), fused GRU epilogues ----------------

struct KD { const _Float16* a; int st; };
struct GA { KD kd[20]; };

// EPI 0 (NG=2): z=sig(g0), r=sig(g1); Z[row,col]=z; Gout[row,col]=(f16)(Hf*r)
// EPI 1 (NG=1): ht=tanh(g0); hn=z*Hf+(1-z)*ht; Hf=hn; Hh=(f16)hn
// EPI 2 (NG=1): EPI1 + fused proj: out[b,t,n] = sum_col hn*Wo[col] + bo
template<int NK, int NG, int EPI>
__global__ __launch_bounds__(256) void k_gemm(GA ga,
    const _Float16* __restrict__ wh0, const _Float16* __restrict__ wl0, const float* __restrict__ b0,
    const _Float16* __restrict__ wh1, const _Float16* __restrict__ wl1, const float* __restrict__ b1,
    float* __restrict__ Z, _Float16* __restrict__ Gout,
    float* __restrict__ Hf, _Float16* __restrict__ Hh,
    const float* __restrict__ Wo, const float* __restrict__ bo,
    float* __restrict__ out, int t){
    int tid = threadIdx.x;
    int lane = tid & 63, wv = tid >> 6, rl = lane & 15, kg = lane >> 4;
    int m0 = blockIdx.x*64 + wv*16;
    f32x4 acc0[4], acc1[4];
    #pragma unroll
    for (int cf=0; cf<4; ++cf){
        acc0[cf][0]=0.f; acc0[cf][1]=0.f; acc0[cf][2]=0.f; acc0[cf][3]=0.f;
        acc1[cf][0]=0.f; acc1[cf][1]=0.f; acc1[cf][2]=0.f; acc1[cf][3]=0.f;
    }
    for (int ks=0; ks<NK; ++ks){
        const _Float16* pa = ga.kd[ks].a + (size_t)(m0+rl)*ga.kd[ks].st + kg*8;
        half8 av = *(const half8*)pa;
        #pragma unroll
        for (int cf=0; cf<4; ++cf){
            size_t wb = ((size_t)(cf*NK + ks)*64 + lane)*8;
            half8 bh = *(const half8*)(wh0 + wb);
            half8 bl = *(const half8*)(wl0 + wb);
            acc0[cf] = __builtin_amdgcn_mfma_f32_16x16x32_f16(av, bh, acc0[cf], 0, 0, 0);
            acc0[cf] = __builtin_amdgcn_mfma_f32_16x16x32_f16(av, bl, acc0[cf], 0, 0, 0);
            if (NG == 2){
                half8 ch = *(const half8*)(wh1 + wb);
                half8 cl = *(const half8*)(wl1 + wb);
                acc1[cf] = __builtin_amdgcn_mfma_f32_16x16x32_f16(av, ch, acc1[cf], 0, 0, 0);
                acc1[cf] = __builtin_amdgcn_mfma_f32_16x16x32_f16(av, cl, acc1[cf], 0, 0, 0);
            }
        }
    }
    if (EPI == 0){
        #pragma unroll
        for (int cf=0; cf<4; ++cf){
            int col = cf*16 + rl;
            float bz = b0[col], br = b1[col];
            #pragma unroll
            for (int i=0;i<4;i++){
                int row = m0 + kg*4 + i;
                float z = 1.f/(1.f+__expf(-(acc0[cf][i] + bz)));
                float r = 1.f/(1.f+__expf(-(acc1[cf][i] + br)));
                size_t ix = (size_t)row*64 + col;
                Z[ix] = z;
                Gout[ix] = (_Float16)(Hf[ix]*r);
            }
        }
    } else {
        float pr[4] = {0.f,0.f,0.f,0.f};
        #pragma unroll
        for (int cf=0; cf<4; ++cf){
            int col = cf*16 + rl;
            float bv = b0[col];
            float wo_c = (EPI == 2) ? Wo[col] : 0.f;
            #pragma unroll
            for (int i=0;i<4;i++){
                int row = m0 + kg*4 + i;
                float ht = tanhf(acc0[cf][i] + bv);
                size_t ix = (size_t)row*64 + col;
                float z = Z[ix];
                float hn = z*Hf[ix] + (1.f-z)*ht;
                Hf[ix] = hn;
                Hh[ix] = (_Float16)hn;
                if (EPI == 2) pr[i] = fmaf(hn, wo_c, pr[i]);
            }
        }
        if (EPI == 2){
            #pragma unroll
            for (int i=0;i<4;i++){
                pr[i] += __shfl_xor(pr[i], 1);
                pr[i] += __shfl_xor(pr[i], 2);
                pr[i] += __shfl_xor(pr[i], 4);
                pr[i] += __shfl_xor(pr[i], 8);
            }
            if (rl == 0){
                float bb = bo[0];
                #pragma unroll
                for (int i=0;i<4;i++){
                    int row = m0 + kg*4 + i;
                    int n = row >> 3, b = row & 7;
                    out[(size_t)(b*SEQT + t)*NNODES + n] = pr[i] + bb;
                }
            }
        }
    }
}

// ---------------- launcher ----------------

extern "C" void kernel_launch(void* const* d_in, const int* in_sizes, int n_in,
                              void* d_out, int out_size, void* d_ws, size_t ws_size,
                              hipStream_t stream){
    (void)in_sizes; (void)n_in; (void)out_size; (void)ws_size;
    const float* x  = (const float*)d_in[0];
    const int*   ei = (const int*)d_in[1];
    const float* Wz[2] = {(const float*)d_in[2],  (const float*)d_in[8]};
    const float* bz[2] = {(const float*)d_in[3],  (const float*)d_in[9]};
    const float* Wr[2] = {(const float*)d_in[4],  (const float*)d_in[10]};
    const float* br[2] = {(const float*)d_in[5],  (const float*)d_in[11]};
    const float* Wh[2] = {(const float*)d_in[6],  (const float*)d_in[12]};
    const float* bh[2] = {(const float*)d_in[7],  (const float*)d_in[13]};
    const float* Wo = (const float*)d_in[14];
    const float* bo = (const float*)d_in[15];
    float* out = (float*)d_out;

    char* p = (char*)d_ws;
    auto alloc = [&](size_t bytes)->char*{
        char* r = p; p += (bytes + 255) & ~(size_t)255; return r;
    };
    const size_t H64  = (size_t)NB*64*2;    // 5.12 MB fp16 64-wide
    const size_t H128 = (size_t)NB*128*2;   // 10.24 MB fp16 128-wide
    const size_t F64  = (size_t)NB*64*4;    // 10.24 MB f32

    _Float16* Xtph = (_Float16*)alloc((size_t)SEQT*NB*2*2);
    float*    h0f = (float*)alloc(F64);
    float*    h1f = (float*)alloc(F64);
    float*    Z0  = (float*)alloc(F64);
    float*    Z1  = (float*)alloc(F64);
    _Float16* h0h = (_Float16*)alloc(H64);
    _Float16* h1h = (_Float16*)alloc(H64);
    _Float16* XTh = (_Float16*)alloc((size_t)NB*32*2);
    _Float16* Th1o = (_Float16*)alloc(H64);
    _Float16* Th1i = (_Float16*)alloc(H64);
    _Float16* Th2o = (_Float16*)alloc(H64);
    _Float16* Th2i = (_Float16*)alloc(H64);
    _Float16* G0L0 = (_Float16*)alloc(H64);
    _Float16* G1o0 = (_Float16*)alloc(H64);
    _Float16* G1i0 = (_Float16*)alloc(H64);
    _Float16* G2o0 = (_Float16*)alloc(H64);
    _Float16* G2i0 = (_Float16*)alloc(H64);
    _Float16* T1o128 = (_Float16*)alloc(H128);
    _Float16* T1i128 = (_Float16*)alloc(H128);
    _Float16* U2o128 = (_Float16*)alloc(H128);
    _Float16* U2i128 = (_Float16*)alloc(H128);
    _Float16* G0p  = (_Float16*)alloc(H64);
    _Float16* G1o1 = (_Float16*)alloc(H64);
    _Float16* G1i1 = (_Float16*)alloc(H64);
    _Float16* G2o1 = (_Float16*)alloc(H64);
    _Float16* G2i1 = (_Float16*)alloc(H64);
    _Float16 *whl0[3][2], *whl1[3][2];
    for (int g=0; g<3; ++g){
        whl0[g][0] = (_Float16*)alloc((size_t)4*11*64*8*2);
        whl0[g][1] = (_Float16*)alloc((size_t)4*11*64*8*2);
        whl1[g][0] = (_Float16*)alloc((size_t)4*20*64*8*2);
        whl1[g][1] = (_Float16*)alloc((size_t)4*20*64*8*2);
    }
    int* deg_out = (int*)alloc(NNODES*4);
    int* deg_in  = (int*)alloc(NNODES*4);
    int* row_ptr = (int*)alloc((NNODES+1)*4);
    int* cursor  = (int*)alloc(NNODES*4);
    int* csr_src = (int*)alloc(NEDGES*4);
    float* csr_wo = (float*)alloc(NEDGES*4);
    float* csr_wi = (float*)alloc(NEDGES*4);

    hipMemsetAsync(deg_out, 0, NNODES*4, stream);
    hipMemsetAsync(deg_in,  0, NNODES*4, stream);
    hipMemsetAsync(cursor,  0, NNODES*4, stream);
    hipMemsetAsync(h0f, 0, F64, stream);
    hipMemsetAsync(h1f, 0, F64, stream);
    hipMemsetAsync(h0h, 0, H64, stream);
    hipMemsetAsync(h1h, 0, H64, stream);
    hipMemsetAsync(XTh, 0, (size_t)NB*32*2, stream);

    count_deg_k<<<(NEDGES+255)/256, 256, 0, stream>>>(ei, deg_out, deg_in);
    scan_k<<<1, 256, 0, stream>>>(deg_in, row_ptr);
    fill_csr_k<<<(NEDGES+255)/256, 256, 0, stream>>>(ei, deg_out, deg_in, row_ptr,
                                                     cursor, csr_src, csr_wo, csr_wi);
    prepack_x_k<<<(SEQT*NB*2+255)/256, 256, 0, stream>>>(x, Xtph);
    const float* Wptr0[3] = {Wz[0], Wr[0], Wh[0]};
    const float* Wptr1[3] = {Wz[1], Wr[1], Wh[1]};
    for (int g=0; g<3; ++g){
        pack_l0_k<<<(4*11*64+255)/256, 256, 0, stream>>>(Wptr0[g], whl0[g][0], whl0[g][1]);
        pack_l1_k<<<(4*20*64+255)/256, 256, 0, stream>>>(Wptr1[g], whl1[g][0], whl1[g][1]);
    }

    // GEMM K-block descriptor tables (strides in halves)
    GA gaL0zr = {}, gaL0h = {}, gaL1zr = {}, gaL1h = {};
    {
        const _Float16* t64[5] = {h0h, Th1o, Th1i, Th2o, Th2i};
        gaL0zr.kd[0] = {XTh, 32};
        for (int s=0; s<5; ++s){
            gaL0zr.kd[1+2*s] = {t64[s], 64};
            gaL0zr.kd[2+2*s] = {t64[s]+32, 64};
        }
        const _Float16* g64[5] = {G0L0, G1o0, G1i0, G2o0, G2i0};
        gaL0h.kd[0] = {XTh, 32};
        for (int s=0; s<5; ++s){
            gaL0h.kd[1+2*s] = {g64[s], 64};
            gaL0h.kd[2+2*s] = {g64[s]+32, 64};
        }
        gaL1zr.kd[0] = {h0h, 64};    gaL1zr.kd[1] = {h0h+32, 64};
        gaL1zr.kd[2] = {h1h, 64};    gaL1zr.kd[3] = {h1h+32, 64};
        const _Float16* t128[4] = {T1o128, T1i128, U2o128, U2i128};
        for (int s=0; s<4; ++s)
            for (int q=0; q<4; ++q)
                gaL1zr.kd[4+4*s+q] = {t128[s]+32*q, 128};
        gaL1h.kd[0] = {h0h, 64};  gaL1h.kd[1] = {h0h+32, 64};
        gaL1h.kd[2] = {G0p, 64};  gaL1h.kd[3] = {G0p+32, 64};
        const _Float16* gh[4] = {G1o1, G1i1, G2o1, G2i1};
        for (int s=0; s<4; ++s){
            gaL1h.kd[4+4*s+0] = {t128[s], 128};
            gaL1h.kd[4+4*s+1] = {t128[s]+32, 128};
            gaL1h.kd[4+4*s+2] = {gh[s], 64};
            gaL1h.kd[4+4*s+3] = {gh[s]+32, 64};
        }
    }

    for (int t=0; t<SEQT; ++t){
        // ---- layer 0 ----
        k_dual_l0zrh<<<NNODES, 64, 0, stream>>>(h0h, Xtph + (size_t)t*NB*2, Th1o, Th1i, XTh,
                                                row_ptr, csr_src, csr_wo, csr_wi);
        k_prop2_l0zrh<<<2*NNODES, 64, 0, stream>>>(Th1o, Th1i, Th2o, Th2i, XTh,
                                                row_ptr, csr_src, csr_wo, csr_wi);
        k_gemm<11,2,0><<<NB/64, 256, 0, stream>>>(gaL0zr,
            whl0[0][0], whl0[0][1], bz[0], whl0[1][0], whl0[1][1], br[0],
            Z0, G0L0, h0f, nullptr, nullptr, nullptr, nullptr, 0);
        k_dualh<64><<<NNODES, 64, 0, stream>>>(G0L0, G1o0, G1i0, row_ptr, csr_src, csr_wo, csr_wi);
        k_prop2h<64><<<2*NNODES, 64, 0, stream>>>(G1o0, G1i0, G2o0, G2i0,
                                                row_ptr, csr_src, csr_wo, csr_wi);
        k_gemm<11,1,1><<<NB/64, 256, 0, stream>>>(gaL0h,
            whl0[2][0], whl0[2][1], bh[0], nullptr, nullptr, nullptr,
            Z0, nullptr, h0f, h0h, nullptr, nullptr, nullptr, 0);
        // ---- layer 1 ----
        k_dual2x64h<<<NNODES, 128, 0, stream>>>(h0h, h1h, T1o128, T1i128,
                                                row_ptr, csr_src, csr_wo, csr_wi);
        k_prop2h<128><<<2*NNODES, 128, 0, stream>>>(T1o128, T1i128, U2o128, U2i128,
                                                row_ptr, csr_src, csr_wo, csr_wi);
        k_gemm<20,2,0><<<NB/64, 256, 0, stream>>>(gaL1zr,
            whl1[0][0], whl1[0][1], bz[1], whl1[1][0], whl1[1][1], br[1],
            Z1, G0p, h1f, nullptr, nullptr, nullptr, nullptr, 0);
        k_dualh<64><<<NNODES, 64, 0, stream>>>(G0p, G1o1, G1i1, row_ptr, csr_src, csr_wo, csr_wi);
        k_prop2h<64><<<2*NNODES, 64, 0, stream>>>(G1o1, G1i1, G2o1, G2i1,
                                                row_ptr, csr_src, csr_wo, csr_wi);
        k_gemm<20,1,2><<<NB/64, 256, 0, stream>>>(gaL1h,
            whl1[2][0], whl1[2][1], bh[1], nullptr, nullptr, nullptr,
            Z1, nullptr, h1f, h1h, Wo, bo, out, t);
    }
}

// Round 5
// 2492.056 us; speedup vs baseline: 3.2517x; 1.2939x over previous
//
#include <hip/hip_runtime.h>
#include <math.h>

#define NNODES 5000
#define NEDGES 50000
#define SEQT 12
#define NB 40000
#define MAXDEG 128

typedef __attribute__((ext_vector_type(8))) _Float16 half8;
typedef __attribute__((ext_vector_type(2))) _Float16 half2v;
typedef __attribute__((ext_vector_type(4))) float f32x4;

// ---------------- setup kernels ----------------

__global__ void count_deg_k(const int* __restrict__ ei, int* deg_out, int* deg_in){
    int e = blockIdx.x*blockDim.x + threadIdx.x;
    if (e < NEDGES){
        atomicAdd(&deg_out[ei[e]], 1);
        atomicAdd(&deg_in[ei[NEDGES + e]], 1);
    }
}

__global__ void scan_k(const int* __restrict__ deg_in, int* __restrict__ row_ptr){
    __shared__ int part[256];
    int tid = threadIdx.x;
    int base = tid*20;
    int loc[20]; int s = 0;
    for (int i=0;i<20;i++){
        int idx = base+i;
        int v = (idx < NNODES) ? deg_in[idx] : 0;
        loc[i] = s; s += v;
    }
    part[tid] = s;
    __syncthreads();
    for (int off=1; off<256; off<<=1){
        int v = (tid>=off) ? part[tid-off] : 0;
        __syncthreads();
        part[tid] += v;
        __syncthreads();
    }
    int prev = (tid==0) ? 0 : part[tid-1];
    for (int i=0;i<20;i++){
        int idx = base+i;
        if (idx < NNODES) row_ptr[idx] = prev + loc[i];
    }
    if (tid==255) row_ptr[NNODES] = part[255];
}

__global__ void fill_csr_k(const int* __restrict__ ei, const int* __restrict__ deg_out,
                           const int* __restrict__ deg_in, const int* __restrict__ row_ptr,
                           int* cursor, int* __restrict__ csr_src,
                           float* __restrict__ csr_wo, float* __restrict__ csr_wi){
    int e = blockIdx.x*blockDim.x + threadIdx.x;
    if (e >= NEDGES) return;
    int s = ei[e], d = ei[NEDGES+e];
    int pos = atomicAdd(&cursor[d], 1);
    int slot = row_ptr[d] + pos;
    csr_src[slot] = s;
    csr_wo[slot] = 1.f/(float)deg_out[s];
    csr_wi[slot] = 1.f/(float)deg_in[d];
}

// pre-pack x for all timesteps: Xtph[t][row][2] fp16, row = n*8+b
__global__ void prepack_x_k(const float* __restrict__ x, _Float16* __restrict__ Xtph){
    int idx = blockIdx.x*256 + threadIdx.x;
    if (idx >= SEQT*NB*2) return;
    int tt = idx / (NB*2);
    int r2 = idx - tt*(NB*2);
    int row = r2 >> 1, f = r2 & 1;
    int n = row >> 3, b = row & 7;
    Xtph[idx] = (_Float16)x[((size_t)(b*SEQT+tt)*NNODES + n)*2 + f];
}

// ---------------- weight packing (refolded basis, split fp16, ks-major MFMA B-frag layout) ----------------
// refolded basis: {T0, T1o, T1i, U2o=Po T1o, U2i=Pi T1i}
// slot 0: W'0 = W[0,0]+W[1,0]-W[0,2]-W[1,2]; 1: W[0,1]; 2: W[1,1]; 3: 2W[0,2]; 4: 2W[1,2]
__device__ __forceinline__ float wfetch(const float* __restrict__ W, int F, int slot, int f, int c){
    const float* p0 = W + ((size_t)0*F + f)*64 + c;
    const float* p1 = W + ((size_t)1*F + f)*64 + c;
    const float* p2 = W + ((size_t)2*F + f)*64 + c;
    const float* p3 = W + ((size_t)3*F + f)*64 + c;
    const float* p4 = W + ((size_t)4*F + f)*64 + c;
    const float* p5 = W + ((size_t)5*F + f)*64 + c;
    switch(slot){
        case 0: return *p0 + *p3 - *p2 - *p5;
        case 1: return *p1;
        case 2: return *p4;
        case 3: return 2.f * *p2;
        default: return 2.f * *p5;
    }
}

// output offset: ((ks*4 + cf)*64 + lane)*8   (ks-major so a K-slice is contiguous)
__global__ void pack_l0_k(const float* __restrict__ W, _Float16* __restrict__ wh, _Float16* __restrict__ wl){
    int idx = blockIdx.x*256 + threadIdx.x;
    if (idx >= 4*11*64) return;
    int lane = idx & 63, rest = idx >> 6;
    int ks = rest % 11, cf = rest / 11;
    int col = cf*16 + (lane & 15);
    int kb = ks*32 + ((lane>>4)<<3);
    size_t o = ((size_t)(ks*4 + cf)*64 + lane)*8;
    for (int j=0;j<8;j++){
        int k = kb + j;
        float v = 0.f;
        if (ks == 0){
            if (k < 10) v = wfetch(W, 66, k>>1, k&1, col);
        } else {
            int slot = (ks-1)>>1;
            int f = 2 + k - 32 - 64*slot;
            v = wfetch(W, 66, slot, f, col);
        }
        _Float16 hh = (_Float16)v;
        wh[o+j] = hh;
        wl[o+j] = (_Float16)(v - (float)hh);
    }
}

__global__ void pack_l1_k(const float* __restrict__ W, _Float16* __restrict__ wh, _Float16* __restrict__ wl){
    int idx = blockIdx.x*256 + threadIdx.x;
    if (idx >= 4*20*64) return;
    int lane = idx & 63, rest = idx >> 6;
    int ks = rest % 20, cf = rest / 20;
    int col = cf*16 + (lane & 15);
    int kb = ks*32 + ((lane>>4)<<3);
    int slot = ks >> 2;
    size_t o = ((size_t)(ks*4 + cf)*64 + lane)*8;
    for (int j=0;j<8;j++){
        int k = kb + j;
        int f = k - slot*128;
        float v = wfetch(W, 128, slot, f, col);
        _Float16 hh = (_Float16)v;
        wh[o+j] = hh;
        wl[o+j] = (_Float16)(v - (float)hh);
    }
}

// ---------------- propagation kernels (fp16, 16B-granule gathers, CSR by dst) ----------------

template<int WH>
__global__ __launch_bounds__(WH) void k_dualh(
    const _Float16* __restrict__ S,
    _Float16* __restrict__ Yo, _Float16* __restrict__ Yi,
    const int* __restrict__ rp, const int* __restrict__ cs,
    const float* __restrict__ cwo, const float* __restrict__ cwi){
    constexpr int SLAB = 8*WH;
    int n = blockIdx.x;
    int beg = rp[n], deg = rp[n+1]-beg;
    int nst = deg < MAXDEG ? deg : MAXDEG;
    __shared__ int s_o[MAXDEG]; __shared__ float swo[MAXDEG], swi[MAXDEG];
    for (int j=threadIdx.x; j<nst; j+=WH){
        s_o[j] = cs[beg+j]*SLAB;
        swo[j] = cwo[beg+j]; swi[j] = cwi[beg+j];
    }
    __syncthreads();
    int off = threadIdx.x*8;
    float ao[8] = {0,0,0,0,0,0,0,0}, ai[8] = {0,0,0,0,0,0,0,0};
    for (int j=0;j<nst;j++){
        half8 v = *(const half8*)(S + s_o[j] + off);
        float wo=swo[j], wi=swi[j];
        #pragma unroll
        for (int e=0;e<8;e++){
            float xv = (float)v[e];
            ao[e]=fmaf(wo,xv,ao[e]); ai[e]=fmaf(wi,xv,ai[e]);
        }
    }
    for (int j=nst;j<deg;j++){
        half8 v = *(const half8*)(S + (size_t)cs[beg+j]*SLAB + off);
        float wo=cwo[beg+j], wi=cwi[beg+j];
        #pragma unroll
        for (int e=0;e<8;e++){
            float xv = (float)v[e];
            ao[e]=fmaf(wo,xv,ao[e]); ai[e]=fmaf(wi,xv,ai[e]);
        }
    }
    half8 po, pi;
    #pragma unroll
    for (int e=0;e<8;e++){ po[e]=(_Float16)ao[e]; pi[e]=(_Float16)ai[e]; }
    *(half8*)(Yo + (size_t)n*SLAB + off) = po;
    *(half8*)(Yi + (size_t)n*SLAB + off) = pi;
}

template<int WH>
__global__ __launch_bounds__(WH) void k_prop2h(
    const _Float16* __restrict__ T1o, const _Float16* __restrict__ T1i,
    _Float16* __restrict__ U2o, _Float16* __restrict__ U2i,
    const int* __restrict__ rp, const int* __restrict__ cs,
    const float* __restrict__ cwo, const float* __restrict__ cwi){
    constexpr int SLAB = 8*WH;
    int bx = blockIdx.x;
    int n = bx >> 1, sel = bx & 1;
    const _Float16* S = sel ? T1i : T1o;
    _Float16* U = sel ? U2i : U2o;
    const float* cw = sel ? cwi : cwo;
    int beg = rp[n], deg = rp[n+1]-beg;
    int nst = deg < MAXDEG ? deg : MAXDEG;
    __shared__ int s_o[MAXDEG]; __shared__ float s_w[MAXDEG];
    for (int j=threadIdx.x; j<nst; j+=WH){
        s_o[j] = cs[beg+j]*SLAB;
        s_w[j] = cw[beg+j];
    }
    __syncthreads();
    int off = threadIdx.x*8;
    float a[8] = {0,0,0,0,0,0,0,0};
    for (int j=0;j<nst;j++){
        half8 v = *(const half8*)(S + s_o[j] + off);
        float w=s_w[j];
        #pragma unroll
        for (int e=0;e<8;e++) a[e]=fmaf(w,(float)v[e],a[e]);
    }
    for (int j=nst;j<deg;j++){
        half8 v = *(const half8*)(S + (size_t)cs[beg+j]*SLAB + off);
        float w=cw[beg+j];
        #pragma unroll
        for (int e=0;e<8;e++) a[e]=fmaf(w,(float)v[e],a[e]);
    }
    half8 p;
    #pragma unroll
    for (int e=0;e<8;e++) p[e]=(_Float16)a[e];
    *(half8*)(U + (size_t)n*SLAB + off) = p;
}

__global__ __launch_bounds__(64) void k_dual_l0zrh(
    const _Float16* __restrict__ h0h, const _Float16* __restrict__ Xt,
    _Float16* __restrict__ T1o, _Float16* __restrict__ T1i, _Float16* __restrict__ XTh,
    const int* __restrict__ rp, const int* __restrict__ cs,
    const float* __restrict__ cwo, const float* __restrict__ cwi){
    int n = blockIdx.x;
    int beg = rp[n], deg = rp[n+1]-beg;
    int nst = deg < MAXDEG ? deg : MAXDEG;
    __shared__ int s_o[MAXDEG]; __shared__ float swo[MAXDEG], swi[MAXDEG];
    for (int j=threadIdx.x; j<nst; j+=64){
        s_o[j] = cs[beg+j]*512;
        swo[j] = cwo[beg+j]; swi[j] = cwi[beg+j];
    }
    __syncthreads();
    int off = threadIdx.x*8;
    {
        float ao[8] = {0,0,0,0,0,0,0,0}, ai[8] = {0,0,0,0,0,0,0,0};
        for (int j=0;j<nst;j++){
            half8 v = *(const half8*)(h0h + s_o[j] + off);
            float wo=swo[j], wi=swi[j];
            #pragma unroll
            for (int e=0;e<8;e++){
                float xv = (float)v[e];
                ao[e]=fmaf(wo,xv,ao[e]); ai[e]=fmaf(wi,xv,ai[e]);
            }
        }
        for (int j=nst;j<deg;j++){
            half8 v = *(const half8*)(h0h + (size_t)cs[beg+j]*512 + off);
            float wo=cwo[beg+j], wi=cwi[beg+j];
            #pragma unroll
            for (int e=0;e<8;e++){
                float xv = (float)v[e];
                ao[e]=fmaf(wo,xv,ao[e]); ai[e]=fmaf(wi,xv,ai[e]);
            }
        }
        half8 po, pi;
        #pragma unroll
        for (int e=0;e<8;e++){ po[e]=(_Float16)ao[e]; pi[e]=(_Float16)ai[e]; }
        *(half8*)(T1o + (size_t)n*512 + off) = po;
        *(half8*)(T1i + (size_t)n*512 + off) = pi;
    }
    if (threadIdx.x < 8){
        int b = threadIdx.x;
        float ax0=0,ax1=0, ay0=0,ay1=0;
        for (int j=0;j<nst;j++){
            int src = s_o[j] >> 9;
            half2v v = *(const half2v*)(Xt + src*16 + b*2);
            float x0=(float)v[0], x1=(float)v[1];
            ax0=fmaf(swo[j],x0,ax0); ax1=fmaf(swo[j],x1,ax1);
            ay0=fmaf(swi[j],x0,ay0); ay1=fmaf(swi[j],x1,ay1);
        }
        for (int j=nst;j<deg;j++){
            int src = cs[beg+j];
            half2v v = *(const half2v*)(Xt + src*16 + b*2);
            float x0=(float)v[0], x1=(float)v[1];
            ax0=fmaf(cwo[beg+j],x0,ax0); ax1=fmaf(cwo[beg+j],x1,ax1);
            ay0=fmaf(cwi[beg+j],x0,ay0); ay1=fmaf(cwi[beg+j],x1,ay1);
        }
        size_t ro = (size_t)(n*8 + b)*32;
        XTh[ro+0] = Xt[(size_t)(n*8+b)*2+0];
        XTh[ro+1] = Xt[(size_t)(n*8+b)*2+1];
        XTh[ro+2] = (_Float16)ax0; XTh[ro+3] = (_Float16)ax1;
        XTh[ro+4] = (_Float16)ay0; XTh[ro+5] = (_Float16)ay1;
    }
}

__global__ __launch_bounds__(64) void k_prop2_l0zrh(
    const _Float16* __restrict__ T1o, const _Float16* __restrict__ T1i,
    _Float16* __restrict__ T2o, _Float16* __restrict__ T2i, _Float16* __restrict__ XTh,
    const int* __restrict__ rp, const int* __restrict__ cs,
    const float* __restrict__ cwo, const float* __restrict__ cwi){
    int bx = blockIdx.x;
    int n = bx >> 1, sel = bx & 1;
    const _Float16* S = sel ? T1i : T1o;
    _Float16* U = sel ? T2i : T2o;
    const float* cw = sel ? cwi : cwo;
    int beg = rp[n], deg = rp[n+1]-beg;
    int nst = deg < MAXDEG ? deg : MAXDEG;
    __shared__ int s_o[MAXDEG]; __shared__ float s_w[MAXDEG];
    for (int j=threadIdx.x; j<nst; j+=64){
        s_o[j] = cs[beg+j]*512;
        s_w[j] = cw[beg+j];
    }
    __syncthreads();
    int off = threadIdx.x*8;
    {
        float a[8] = {0,0,0,0,0,0,0,0};
        for (int j=0;j<nst;j++){
            half8 v = *(const half8*)(S + s_o[j] + off);
            float w=s_w[j];
            #pragma unroll
            for (int e=0;e<8;e++) a[e]=fmaf(w,(float)v[e],a[e]);
        }
        for (int j=nst;j<deg;j++){
            half8 v = *(const half8*)(S + (size_t)cs[beg+j]*512 + off);
            float w=cw[beg+j];
            #pragma unroll
            for (int e=0;e<8;e++) a[e]=fmaf(w,(float)v[e],a[e]);
        }
        half8 p;
        #pragma unroll
        for (int e=0;e<8;e++) p[e]=(_Float16)a[e];
        *(half8*)(U + (size_t)n*512 + off) = p;
    }
    if (threadIdx.x < 8){
        int b = threadIdx.x;
        int xo = 2 + 2*sel;
        float a0=0,a1=0;
        for (int j=0;j<nst;j++){
            int src = s_o[j] >> 9;
            half2v v = *(const half2v*)(XTh + (size_t)src*256 + b*32 + xo);
            a0=fmaf(s_w[j],(float)v[0],a0); a1=fmaf(s_w[j],(float)v[1],a1);
        }
        for (int j=nst;j<deg;j++){
            int src = cs[beg+j];
            half2v v = *(const half2v*)(XTh + (size_t)src*256 + b*32 + xo);
            a0=fmaf(cw[beg+j],(float)v[0],a0); a1=fmaf(cw[beg+j],(float)v[1],a1);
        }
        size_t ro = (size_t)(n*8 + b)*32 + 6 + 2*sel;
        XTh[ro+0] = (_Float16)a0; XTh[ro+1] = (_Float16)a1;
    }
}

__global__ __launch_bounds__(128) void k_dual2x64h(
    const _Float16* __restrict__ h0h, const _Float16* __restrict__ h1h,
    _Float16* __restrict__ T1o, _Float16* __restrict__ T1i,
    const int* __restrict__ rp, const int* __restrict__ cs,
    const float* __restrict__ cwo, const float* __restrict__ cwi){
    int n = blockIdx.x;
    int beg = rp[n], deg = rp[n+1]-beg;
    int nst = deg < MAXDEG ? deg : MAXDEG;
    __shared__ int s_o[MAXDEG]; __shared__ float swo[MAXDEG], swi[MAXDEG];
    for (int j=threadIdx.x; j<nst; j+=128){
        s_o[j] = cs[beg+j]*512;
        swo[j] = cwo[beg+j]; swi[j] = cwi[beg+j];
    }
    __syncthreads();
    int off = threadIdx.x*8;
    int b = off >> 7, c = off & 127;
    const _Float16* S = (c < 64) ? h0h : h1h;
    int soff = b*64 + (c & 63);
    float ao[8] = {0,0,0,0,0,0,0,0}, ai[8] = {0,0,0,0,0,0,0,0};
    for (int j=0;j<nst;j++){
        half8 v = *(const half8*)(S + s_o[j] + soff);
        float wo=swo[j], wi=swi[j];
        #pragma unroll
        for (int e=0;e<8;e++){
            float xv = (float)v[e];
            ao[e]=fmaf(wo,xv,ao[e]); ai[e]=fmaf(wi,xv,ai[e]);
        }
    }
    for (int j=nst;j<deg;j++){
        half8 v = *(const half8*)(S + (size_t)cs[beg+j]*512 + soff);
        float wo=cwo[beg+j], wi=cwi[beg+j];
        #pragma unroll
        for (int e=0;e<8;e++){
            float xv = (float)v[e];
            ao[e]=fmaf(wo,xv,ao[e]); ai[e]=fmaf(wi,xv,ai[e]);
        }
    }
    half8 po, pi;
    #pragma unroll
    for (int e=0;e<8;e++){ po[e]=(_Float16)ao[e]; pi[e]=(_Float16)ai[e]; }
    *(half8*)(T1o + (size_t)n*1024 + off) = po;
    *(half8*)(T1i + (size_t)n*1024 + off) = pi;
}

// ---------------- MFMA f16 GEMM: LDS-staged B (double-buffered), 32x32 wave tiles ----------------

struct KD { const _Float16* a; int st; };
struct GA { KD kd[20]; };

// wave wv: rows m0=bx*64+(wv&1)*32 (2 frags of 16), cols (wv>>1)*32 (2 cf frags)
// EPI 0 (NG=2): z=sig(g0), r=sig(g1); Z=z; Gout=(f16)(Hf*r)
// EPI 1 (NG=1): ht=tanh(g0); hn=z*Hf+(1-z)*ht; Hf=hn; Hh=(f16)hn
// EPI 2 (NG=1): EPI1 + fused proj via LDS cross-wave reduce
template<int NK, int NG, int EPI>
__global__ __launch_bounds__(256) void k_gemm(GA ga,
    const _Float16* __restrict__ wh0, const _Float16* __restrict__ wl0, const float* __restrict__ b0,
    const _Float16* __restrict__ wh1, const _Float16* __restrict__ wl1, const float* __restrict__ b1,
    float* __restrict__ Z, _Float16* __restrict__ Gout,
    float* __restrict__ Hf, _Float16* __restrict__ Hh,
    const float* __restrict__ Wo, const float* __restrict__ bo,
    float* __restrict__ out, int t){
    constexpr int NT = NG*2;
    __shared__ _Float16 ldsb[2][NT*2048];
    __shared__ float spr[4][32];
    const int tid = threadIdx.x;
    const int lane = tid & 63, wv = tid >> 6, rl = lane & 15, kg = lane >> 4;
    const int m0 = blockIdx.x*64 + (wv&1)*32;
    const int cfb = (wv>>1)*2;
    const _Float16* wsrc[4] = {wh0, wl0, wh1, wl1};

    half8 srg[NT];
    half8 a0, a1, a0n, a1n;

    auto sload = [&](int ks){
        #pragma unroll
        for (int j=0;j<NT;j++)
            srg[j] = *(const half8*)(wsrc[j] + (size_t)ks*2048 + tid*8);
    };
    auto swrite = [&](int buf){
        #pragma unroll
        for (int j=0;j<NT;j++)
            *(half8*)&ldsb[buf][j*2048 + tid*8] = srg[j];
    };
    auto aload = [&](int ks, half8& x0, half8& x1){
        const _Float16* base = ga.kd[ks].a;
        const int st = ga.kd[ks].st;
        x0 = *(const half8*)(base + (size_t)(m0+rl)*st + kg*8);
        x1 = *(const half8*)(base + (size_t)(m0+16+rl)*st + kg*8);
    };

    f32x4 acc[NG][2][2];
    #pragma unroll
    for (int g=0; g<NG; ++g)
        #pragma unroll
        for (int cc=0; cc<2; ++cc)
            #pragma unroll
            for (int mr=0; mr<2; ++mr){
                acc[g][cc][mr][0]=0.f; acc[g][cc][mr][1]=0.f;
                acc[g][cc][mr][2]=0.f; acc[g][cc][mr][3]=0.f;
            }

    sload(0); swrite(0);
    if (NK>1) sload(1);
    aload(0, a0, a1);
    __syncthreads();
    for (int ks=0; ks<NK; ++ks){
        const int cur = ks & 1;
        if (ks+1 < NK){ swrite(cur^1); aload(ks+1, a0n, a1n); }
        if (ks+2 < NK) sload(ks+2);
        #pragma unroll
        for (int g=0; g<NG; ++g){
            #pragma unroll
            for (int s=0; s<2; ++s){
                const int jt = g*2+s;
                #pragma unroll
                for (int cc=0; cc<2; ++cc){
                    half8 bv = *(const half8*)&ldsb[cur][jt*2048 + (cfb+cc)*512 + lane*8];
                    acc[g][cc][0] = __builtin_amdgcn_mfma_f32_16x16x32_f16(a0, bv, acc[g][cc][0], 0, 0, 0);
                    acc[g][cc][1] = __builtin_amdgcn_mfma_f32_16x16x32_f16(a1, bv, acc[g][cc][1], 0, 0, 0);
                }
            }
        }
        __syncthreads();
        a0 = a0n; a1 = a1n;
    }

    if constexpr (EPI == 0){
        #pragma unroll
        for (int cc=0; cc<2; ++cc){
            const int col = (cfb+cc)*16 + rl;
            float bzv = b0[col], brv = b1[col];
            #pragma unroll
            for (int mr=0; mr<2; ++mr)
                #pragma unroll
                for (int i=0;i<4;i++){
                    int row = m0 + mr*16 + kg*4 + i;
                    float z = 1.f/(1.f+__expf(-(acc[0][cc][mr][i] + bzv)));
                    float r = 1.f/(1.f+__expf(-(acc[NG-1][cc][mr][i] + brv)));
                    size_t ix = (size_t)row*64 + col;
                    Z[ix] = z;
                    Gout[ix] = (_Float16)(Hf[ix]*r);
                }
        }
    } else {
        float pr[2][4] = {{0.f,0.f,0.f,0.f},{0.f,0.f,0.f,0.f}};
        #pragma unroll
        for (int cc=0; cc<2; ++cc){
            const int col = (cfb+cc)*16 + rl;
            float bv = b0[col];
            float wo_c = 0.f;
            if constexpr (EPI == 2) wo_c = Wo[col];
            #pragma unroll
            for (int mr=0; mr<2; ++mr)
                #pragma unroll
                for (int i=0;i<4;i++){
                    int row = m0 + mr*16 + kg*4 + i;
                    float ht = tanhf(acc[0][cc][mr][i] + bv);
                    size_t ix = (size_t)row*64 + col;
                    float z = Z[ix];
                    float hn = z*Hf[ix] + (1.f-z)*ht;
                    Hf[ix] = hn;
                    Hh[ix] = (_Float16)hn;
                    if constexpr (EPI == 2) pr[mr][i] = fmaf(hn, wo_c, pr[mr][i]);
                }
        }
        if constexpr (EPI == 2){
            #pragma unroll
            for (int mr=0; mr<2; ++mr)
                #pragma unroll
                for (int i=0;i<4;i++){
                    float v = pr[mr][i];
                    v += __shfl_xor(v, 1);
                    v += __shfl_xor(v, 2);
                    v += __shfl_xor(v, 4);
                    v += __shfl_xor(v, 8);
                    if (rl == 0) spr[wv][mr*16 + kg*4 + i] = v;
                }
            __syncthreads();
            if (tid < 64){
                int r = tid;
                float v = spr[r>>5][r&31] + spr[(r>>5)|2][r&31] + bo[0];
                int row = blockIdx.x*64 + r;
                int n = row >> 3, b = row & 7;
                out[(size_t)(b*SEQT + t)*NNODES + n] = v;
            }
        }
    }
}

// ---------------- launcher ----------------

extern "C" void kernel_launch(void* const* d_in, const int* in_sizes, int n_in,
                              void* d_out, int out_size, void* d_ws, size_t ws_size,
                              hipStream_t stream){
    (void)in_sizes; (void)n_in; (void)out_size; (void)ws_size;
    const float* x  = (const float*)d_in[0];
    const int*   ei = (const int*)d_in[1];
    const float* Wz[2] = {(const float*)d_in[2],  (const float*)d_in[8]};
    const float* bz[2] = {(const float*)d_in[3],  (const float*)d_in[9]};
    const float* Wr[2] = {(const float*)d_in[4],  (const float*)d_in[10]};
    const float* br[2] = {(const float*)d_in[5],  (const float*)d_in[11]};
    const float* Wh[2] = {(const float*)d_in[6],  (const float*)d_in[12]};
    const float* bh[2] = {(const float*)d_in[7],  (const float*)d_in[13]};
    const float* Wo = (const float*)d_in[14];
    const float* bo = (const float*)d_in[15];
    float* out = (float*)d_out;

    char* p = (char*)d_ws;
    auto alloc = [&](size_t bytes)->char*{
        char* r = p; p += (bytes + 255) & ~(size_t)255; return r;
    };
    const size_t H64  = (size_t)NB*64*2;
    const size_t H128 = (size_t)NB*128*2;
    const size_t F64  = (size_t)NB*64*4;

    _Float16* Xtph = (_Float16*)alloc((size_t)SEQT*NB*2*2);
    float*    h0f = (float*)alloc(F64);
    float*    h1f = (float*)alloc(F64);
    float*    Z0  = (float*)alloc(F64);
    float*    Z1  = (float*)alloc(F64);
    _Float16* h0h = (_Float16*)alloc(H64);
    _Float16* h1h = (_Float16*)alloc(H64);
    _Float16* XTh = (_Float16*)alloc((size_t)NB*32*2);
    _Float16* Th1o = (_Float16*)alloc(H64);
    _Float16* Th1i = (_Float16*)alloc(H64);
    _Float16* Th2o = (_Float16*)alloc(H64);
    _Float16* Th2i = (_Float16*)alloc(H64);
    _Float16* G0L0 = (_Float16*)alloc(H64);
    _Float16* G1o0 = (_Float16*)alloc(H64);
    _Float16* G1i0 = (_Float16*)alloc(H64);
    _Float16* G2o0 = (_Float16*)alloc(H64);
    _Float16* G2i0 = (_Float16*)alloc(H64);
    _Float16* T1o128 = (_Float16*)alloc(H128);
    _Float16* T1i128 = (_Float16*)alloc(H128);
    _Float16* U2o128 = (_Float16*)alloc(H128);
    _Float16* U2i128 = (_Float16*)alloc(H128);
    _Float16* G0p  = (_Float16*)alloc(H64);
    _Float16* G1o1 = (_Float16*)alloc(H64);
    _Float16* G1i1 = (_Float16*)alloc(H64);
    _Float16* G2o1 = (_Float16*)alloc(H64);
    _Float16* G2i1 = (_Float16*)alloc(H64);
    _Float16 *whl0[3][2], *whl1[3][2];
    for (int g=0; g<3; ++g){
        whl0[g][0] = (_Float16*)alloc((size_t)4*11*64*8*2);
        whl0[g][1] = (_Float16*)alloc((size_t)4*11*64*8*2);
        whl1[g][0] = (_Float16*)alloc((size_t)4*20*64*8*2);
        whl1[g][1] = (_Float16*)alloc((size_t)4*20*64*8*2);
    }
    int* deg_out = (int*)alloc(NNODES*4);
    int* deg_in  = (int*)alloc(NNODES*4);
    int* row_ptr = (int*)alloc((NNODES+1)*4);
    int* cursor  = (int*)alloc(NNODES*4);
    int* csr_src = (int*)alloc(NEDGES*4);
    float* csr_wo = (float*)alloc(NEDGES*4);
    float* csr_wi = (float*)alloc(NEDGES*4);

    hipMemsetAsync(deg_out, 0, NNODES*4, stream);
    hipMemsetAsync(deg_in,  0, NNODES*4, stream);
    hipMemsetAsync(cursor,  0, NNODES*4, stream);
    hipMemsetAsync(h0f, 0, F64, stream);
    hipMemsetAsync(h1f, 0, F64, stream);
    hipMemsetAsync(h0h, 0, H64, stream);
    hipMemsetAsync(h1h, 0, H64, stream);
    hipMemsetAsync(XTh, 0, (size_t)NB*32*2, stream);

    count_deg_k<<<(NEDGES+255)/256, 256, 0, stream>>>(ei, deg_out, deg_in);
    scan_k<<<1, 256, 0, stream>>>(deg_in, row_ptr);
    fill_csr_k<<<(NEDGES+255)/256, 256, 0, stream>>>(ei, deg_out, deg_in, row_ptr,
                                                     cursor, csr_src, csr_wo, csr_wi);
    prepack_x_k<<<(SEQT*NB*2+255)/256, 256, 0, stream>>>(x, Xtph);
    const float* Wptr0[3] = {Wz[0], Wr[0], Wh[0]};
    const float* Wptr1[3] = {Wz[1], Wr[1], Wh[1]};
    for (int g=0; g<3; ++g){
        pack_l0_k<<<(4*11*64+255)/256, 256, 0, stream>>>(Wptr0[g], whl0[g][0], whl0[g][1]);
        pack_l1_k<<<(4*20*64+255)/256, 256, 0, stream>>>(Wptr1[g], whl1[g][0], whl1[g][1]);
    }

    GA gaL0zr = {}, gaL0h = {}, gaL1zr = {}, gaL1h = {};
    {
        const _Float16* t64[5] = {h0h, Th1o, Th1i, Th2o, Th2i};
        gaL0zr.kd[0] = {XTh, 32};
        for (int s=0; s<5; ++s){
            gaL0zr.kd[1+2*s] = {t64[s], 64};
            gaL0zr.kd[2+2*s] = {t64[s]+32, 64};
        }
        const _Float16* g64[5] = {G0L0, G1o0, G1i0, G2o0, G2i0};
        gaL0h.kd[0] = {XTh, 32};
        for (int s=0; s<5; ++s){
            gaL0h.kd[1+2*s] = {g64[s], 64};
            gaL0h.kd[2+2*s] = {g64[s]+32, 64};
        }
        gaL1zr.kd[0] = {h0h, 64};    gaL1zr.kd[1] = {h0h+32, 64};
        gaL1zr.kd[2] = {h1h, 64};    gaL1zr.kd[3] = {h1h+32, 64};
        const _Float16* t128[4] = {T1o128, T1i128, U2o128, U2i128};
        for (int s=0; s<4; ++s)
            for (int q=0; q<4; ++q)
                gaL1zr.kd[4+4*s+q] = {t128[s]+32*q, 128};
        gaL1h.kd[0] = {h0h, 64};  gaL1h.kd[1] = {h0h+32, 64};
        gaL1h.kd[2] = {G0p, 64};  gaL1h.kd[3] = {G0p+32, 64};
        const _Float16* gh[4] = {G1o1, G1i1, G2o1, G2i1};
        for (int s=0; s<4; ++s){
            gaL1h.kd[4+4*s+0] = {t128[s], 128};
            gaL1h.kd[4+4*s+1] = {t128[s]+32, 128};
            gaL1h.kd[4+4*s+2] = {gh[s], 64};
            gaL1h.kd[4+4*s+3] = {gh[s]+32, 64};
        }
    }

    for (int t=0; t<SEQT; ++t){
        // ---- layer 0 ----
        k_dual_l0zrh<<<NNODES, 64, 0, stream>>>(h0h, Xtph + (size_t)t*NB*2, Th1o, Th1i, XTh,
                                                row_ptr, csr_src, csr_wo, csr_wi);
        k_prop2_l0zrh<<<2*NNODES, 64, 0, stream>>>(Th1o, Th1i, Th2o, Th2i, XTh,
                                                row_ptr, csr_src, csr_wo, csr_wi);
        k_gemm<11,2,0><<<NB/64, 256, 0, stream>>>(gaL0zr,
            whl0[0][0], whl0[0][1], bz[0], whl0[1][0], whl0[1][1], br[0],
            Z0, G0L0, h0f, nullptr, nullptr, nullptr, nullptr, 0);
        k_dualh<64><<<NNODES, 64, 0, stream>>>(G0L0, G1o0, G1i0, row_ptr, csr_src, csr_wo, csr_wi);
        k_prop2h<64><<<2*NNODES, 64, 0, stream>>>(G1o0, G1i0, G2o0, G2i0,
                                                row_ptr, csr_src, csr_wo, csr_wi);
        k_gemm<11,1,1><<<NB/64, 256, 0, stream>>>(gaL0h,
            whl0[2][0], whl0[2][1], bh[0], nullptr, nullptr, nullptr,
            Z0, nullptr, h0f, h0h, nullptr, nullptr, nullptr, 0);
        // ---- layer 1 ----
        k_dual2x64h<<<NNODES, 128, 0, stream>>>(h0h, h1h, T1o128, T1i128,
                                                row_ptr, csr_src, csr_wo, csr_wi);
        k_prop2h<128><<<2*NNODES, 128, 0, stream>>>(T1o128, T1i128, U2o128, U2i128,
                                                row_ptr, csr_src, csr_wo, csr_wi);
        k_gemm<20,2,0><<<NB/64, 256, 0, stream>>>(gaL1zr,
            whl1[0][0], whl1[0][1], bz[1], whl1[1][0], whl1[1][1], br[1],
            Z1, G0p, h1f, nullptr, nullptr, nullptr, nullptr, 0);
        k_dualh<64><<<NNODES, 64, 0, stream>>>(G0p, G1o1, G1i1, row_ptr, csr_src, csr_wo, csr_wi);
        k_prop2h<64><<<2*NNODES, 64, 0, stream>>>(G1o1, G1i1, G2o1, G2i1,
                                                row_ptr, csr_src, csr_wo, csr_wi);
        k_gemm<20,1,2><<<NB/64, 256, 0, stream>>>(gaL1h,
            whl1[2][0], whl1[2][1], bh[1], nullptr, nullptr, nullptr,
            Z1, nullptr, h1f, h1h, Wo, bo, out, t);
    }
}